// Round 1
// baseline (517.423 us; speedup 1.0000x reference)
//
#include <hip/hip_runtime.h>

using u16    = unsigned short;
using bf16x8 = __attribute__((ext_vector_type(8))) short;
using bf16x4 = __attribute__((ext_vector_type(4))) short;
using f32x4  = __attribute__((ext_vector_type(4))) float;
using i32x4  = __attribute__((ext_vector_type(4))) int;

__device__ __forceinline__ u16 f2b(float f) {
  unsigned u = __builtin_bit_cast(unsigned, f);
  u = (u + 0x7fffu + ((u >> 16) & 1u)) >> 16;
  return (u16)u;
}
__device__ __forceinline__ float b2f(u16 h) {
  return __builtin_bit_cast(float, ((unsigned)h) << 16);
}

// ---------------- weight convert + transpose: wT[n*K+k] = w[k*N+n] (bf16) ----
__global__ void wconv_kernel(const float* __restrict__ src, u16* __restrict__ dst,
                             int K, int N) {
  int idx = blockIdx.x * 256 + threadIdx.x;
  if (idx < K * N) {
    int n = idx / K, k = idx - n * K;
    dst[idx] = f2b(src[(size_t)k * N + n]);
  }
}

// ---------------- relative-bias pre-pack into per-lane fragment layout -------
// biasp[((h*36+kt)*256 + tid)*16 + qc*4 + r] = bias[h][q][k], bf16
//   q = (tid>>6)*64 + qc*16 + (tid&15), k = kt*16 + ((tid>>4)&3)*4 + r
__global__ void bias_pack_kernel(const float* __restrict__ table, u16* __restrict__ biasp) {
  int bid = blockIdx.x;            // h*36 + kt
  int h = bid / 36, kt = bid - h * 36;
  int t = threadIdx.x;
  int l = t & 63, w = t >> 6;
  int lo = l & 15, lg = l >> 4;
  u16 out[16];
#pragma unroll
  for (int qc = 0; qc < 4; ++qc)
#pragma unroll
    for (int r = 0; r < 4; ++r) {
      int q = w * 64 + qc * 16 + lo;
      int k = kt * 16 + lg * 4 + r;
      int i = q >> 4, j = q & 15;
      int oi = k / 24, oj = k - oi * 24;
      int idx = (i - oi + 23) * 39 + (j - oj + 23);
      out[qc * 4 + r] = f2b(table[idx * 6 + h]);
    }
  u16* dst = biasp + ((size_t)(bid * 256 + t)) * 16;
  *(i32x4*)dst = *(const i32x4*)out;
  *(i32x4*)(dst + 8) = *(const i32x4*)(out + 8);
}

// ---------------- LayerNorm (192 cols) fp32 -> bf16 -------------------------
__global__ __launch_bounds__(256) void ln_kernel(const float* __restrict__ xin,
                                                 const float* __restrict__ g,
                                                 const float* __restrict__ b,
                                                 u16* __restrict__ out) {
  int row = blockIdx.x * 4 + (threadIdx.x >> 6);
  int l = threadIdx.x & 63;
  const float* xr = xin + (size_t)row * 192;
  float v0 = xr[l], v1 = xr[l + 64], v2 = xr[l + 128];
  float s1 = v0 + v1 + v2;
  float s2 = v0 * v0 + v1 * v1 + v2 * v2;
#pragma unroll
  for (int off = 32; off; off >>= 1) {
    s1 += __shfl_xor(s1, off);
    s2 += __shfl_xor(s2, off);
  }
  float mu = s1 * (1.0f / 192.0f);
  float var = s2 * (1.0f / 192.0f) - mu * mu;
  float rs = rsqrtf(var + 1e-5f);
  u16* orow = out + (size_t)row * 192;
  orow[l]       = f2b((v0 - mu) * rs * g[l]       + b[l]);
  orow[l + 64]  = f2b((v1 - mu) * rs * g[l + 64]  + b[l + 64]);
  orow[l + 128] = f2b((v2 - mu) * rs * g[l + 128] + b[l + 128]);
}

// ---------------- generic bf16 GEMM: C[M][N] = A[M][K] * WT[N][K]^T ---------
// BM=128, BN=64, 4 waves (2x2), wave tile 64x32, mfma 16x16x32 bf16.
// EPI 0: out bf16 = acc+bias ; EPI 1: out fp32 = acc+bias+res ; EPI 2: bf16 gelu(acc+bias)
template <int N, int K, int EPI>
__global__ __launch_bounds__(256, 2) void gemm_kernel(
    const u16* __restrict__ A, const u16* __restrict__ WT,
    const float* __restrict__ bias, const float* __restrict__ res,
    void* __restrict__ outp) {
  __shared__ u16 As[128 * 200];
  __shared__ u16 Ws[64 * 200];
  const int t = threadIdx.x;
  const int l = t & 63, w = t >> 6;
  const int lo = l & 15, lg = l >> 4;
  const int bm0 = blockIdx.x * 128, bn0 = blockIdx.y * 64;
  const int wr = (w >> 1) * 64, wc = (w & 1) * 32;
  f32x4 acc[4][2] = {};
  for (int c0 = 0; c0 < K; c0 += 192) {
    if (c0) __syncthreads();
#pragma unroll
    for (int i = 0; i < 12; ++i) {
      int u = t + i * 256;
      int row = u / 24, cc = (u - row * 24) * 8;
      *(i32x4*)&As[row * 200 + cc] = *(const i32x4*)&A[(size_t)(bm0 + row) * K + c0 + cc];
    }
#pragma unroll
    for (int i = 0; i < 6; ++i) {
      int u = t + i * 256;
      int row = u / 24, cc = (u - row * 24) * 8;
      *(i32x4*)&Ws[row * 200 + cc] = *(const i32x4*)&WT[(size_t)(bn0 + row) * K + c0 + cc];
    }
    __syncthreads();
#pragma unroll
    for (int kk = 0; kk < 6; ++kk) {
      bf16x8 b0 = *(const bf16x8*)&Ws[(wc + lo) * 200 + kk * 32 + lg * 8];
      bf16x8 b1 = *(const bf16x8*)&Ws[(wc + 16 + lo) * 200 + kk * 32 + lg * 8];
#pragma unroll
      for (int mi = 0; mi < 4; ++mi) {
        bf16x8 a = *(const bf16x8*)&As[(wr + mi * 16 + lo) * 200 + kk * 32 + lg * 8];
        acc[mi][0] = __builtin_amdgcn_mfma_f32_16x16x32_bf16(a, b0, acc[mi][0], 0, 0, 0);
        acc[mi][1] = __builtin_amdgcn_mfma_f32_16x16x32_bf16(a, b1, acc[mi][1], 0, 0, 0);
      }
    }
  }
#pragma unroll
  for (int ni = 0; ni < 2; ++ni) {
    int n = bn0 + wc + ni * 16 + lo;
    float bs = bias[n];
#pragma unroll
    for (int mi = 0; mi < 4; ++mi)
#pragma unroll
      for (int r = 0; r < 4; ++r) {
        int m = bm0 + wr + mi * 16 + lg * 4 + r;
        float v = acc[mi][ni][r] + bs;
        if constexpr (EPI == 0) {
          ((u16*)outp)[(size_t)m * N + n] = f2b(v);
        } else if constexpr (EPI == 1) {
          ((float*)outp)[(size_t)m * N + n] = v + res[(size_t)m * N + n];
        } else {
          float gg = 0.5f * v * (1.0f + erff(v * 0.70710678118654752f));
          ((u16*)outp)[(size_t)m * N + n] = f2b(gg);
        }
      }
  }
}

// ---------------- attention: one block per (window, head) -------------------
#define ATT_SCALE 0.17677669529663687f
__global__ __launch_bounds__(256, 1) void attn_kernel(const u16* __restrict__ qkv,
                                                      const u16* __restrict__ biasp,
                                                      u16* __restrict__ o_out) {
  __shared__ u16 Kl[576 * 40];
  __shared__ u16 Vl[576 * 40];
  const int bx = blockIdx.x;
  const int h = bx % 6;
  const int wid = bx / 6;
  const int bb = wid >> 6, wy = (wid >> 3) & 7, wx = wid & 7;
  const int t = threadIdx.x, l = t & 63, w = t >> 6;
  const int lo = l & 15, lg = l >> 4;

  // stage K and V (24x24 overlapping window, zero-padded at image edges)
#pragma unroll
  for (int i2 = 0; i2 < 9; ++i2) {
    int u = t + i2 * 256;                 // 2304 units = 576 pos x 4 quarters
    int pos = u >> 2, d0 = (u & 3) * 8;
    int oi = pos / 24, oj = pos - oi * 24;
    int y = wy * 16 - 4 + oi, x = wx * 16 - 4 + oj;
    i32x4 kv = {0, 0, 0, 0}, vv = {0, 0, 0, 0};
    if ((unsigned)y < 128u && (unsigned)x < 128u) {
      const u16* s = qkv + (size_t)((bb << 14) + y * 128 + x) * 576 + h * 32 + d0;
      kv = *(const i32x4*)(s + 192);
      vv = *(const i32x4*)(s + 384);
    }
    *(i32x4*)&Kl[pos * 40 + d0] = kv;
    *(i32x4*)&Vl[pos * 40 + d0] = vv;
  }

  // Q fragments: B-operand layout (col = q = lo, k-dims = lg*8..+7)
  bf16x8 qf[4];
#pragma unroll
  for (int qc = 0; qc < 4; ++qc) {
    int yy = wy * 16 + w * 4 + qc, xx = wx * 16 + lo;
    qf[qc] = *(const bf16x8*)(qkv + (size_t)((bb << 14) + yy * 128 + xx) * 576 + h * 32 + lg * 8);
  }
  __syncthreads();

  // pass 1: row max (lane-local q = lo)
  float mx[4] = {-1e30f, -1e30f, -1e30f, -1e30f};
  for (int kt = 0; kt < 36; ++kt) {
    bf16x8 kf = *(const bf16x8*)&Kl[(kt * 16 + lo) * 40 + lg * 8];
    const u16* bp = biasp + ((size_t)(h * 36 + kt) * 256 + t) * 16;
    bf16x8 bb0 = *(const bf16x8*)bp;
    bf16x8 bb1 = *(const bf16x8*)(bp + 8);
#pragma unroll
    for (int qc = 0; qc < 4; ++qc) {
      f32x4 z = {};
      f32x4 c = __builtin_amdgcn_mfma_f32_16x16x32_bf16(kf, qf[qc], z, 0, 0, 0);
#pragma unroll
      for (int r = 0; r < 4; ++r) {
        float bias = b2f((u16)(qc < 2 ? bb0[qc * 4 + r] : bb1[(qc - 2) * 4 + r]));
        float s = fmaf(c[r], ATT_SCALE, bias);
        mx[qc] = fmaxf(mx[qc], s);
      }
    }
  }
#pragma unroll
  for (int qc = 0; qc < 4; ++qc) {
    mx[qc] = fmaxf(mx[qc], __shfl_xor(mx[qc], 16));
    mx[qc] = fmaxf(mx[qc], __shfl_xor(mx[qc], 32));
  }

  // pass 2: exp + PV (S^T C-frag doubles as PV A-frag, no cross-lane moves)
  float ls[4] = {0.0f, 0.0f, 0.0f, 0.0f};
  f32x4 oacc[4][2] = {};
  for (int kt = 0; kt < 36; ++kt) {
    bf16x8 kf = *(const bf16x8*)&Kl[(kt * 16 + lo) * 40 + lg * 8];
    const u16* bp = biasp + ((size_t)(h * 36 + kt) * 256 + t) * 16;
    bf16x8 bb0 = *(const bf16x8*)bp;
    bf16x8 bb1 = *(const bf16x8*)(bp + 8);
    bf16x4 pa[4];
#pragma unroll
    for (int qc = 0; qc < 4; ++qc) {
      f32x4 z = {};
      f32x4 c = __builtin_amdgcn_mfma_f32_16x16x32_bf16(kf, qf[qc], z, 0, 0, 0);
      float p0 = __expf(fmaf(c[0], ATT_SCALE, b2f((u16)(qc < 2 ? bb0[qc * 4 + 0] : bb1[(qc - 2) * 4 + 0]))) - mx[qc]);
      float p1 = __expf(fmaf(c[1], ATT_SCALE, b2f((u16)(qc < 2 ? bb0[qc * 4 + 1] : bb1[(qc - 2) * 4 + 1]))) - mx[qc]);
      float p2 = __expf(fmaf(c[2], ATT_SCALE, b2f((u16)(qc < 2 ? bb0[qc * 4 + 2] : bb1[(qc - 2) * 4 + 2]))) - mx[qc]);
      float p3 = __expf(fmaf(c[3], ATT_SCALE, b2f((u16)(qc < 2 ? bb0[qc * 4 + 3] : bb1[(qc - 2) * 4 + 3]))) - mx[qc]);
      ls[qc] += p0 + p1 + p2 + p3;
      bf16x4 pv = {(short)f2b(p0), (short)f2b(p1), (short)f2b(p2), (short)f2b(p3)};
      pa[qc] = pv;
    }
#pragma unroll
    for (int dh = 0; dh < 2; ++dh) {
      bf16x4 vb;
#pragma unroll
      for (int jj = 0; jj < 4; ++jj)
        vb[jj] = (short)Vl[(kt * 16 + lg * 4 + jj) * 40 + dh * 16 + lo];
#pragma unroll
      for (int qc = 0; qc < 4; ++qc)
        oacc[qc][dh] = __builtin_amdgcn_mfma_f32_16x16x16bf16_1k(pa[qc], vb, oacc[qc][dh], 0, 0, 0);
    }
  }

  // normalize + store
#pragma unroll
  for (int qc = 0; qc < 4; ++qc) {
    float s = ls[qc];
    s += __shfl_xor(s, 16);
    s += __shfl_xor(s, 32);
    float linv = 1.0f / s;
#pragma unroll
    for (int r = 0; r < 4; ++r) {
      float lv = __shfl(linv, lg * 4 + r);
      int yy = wy * 16 + w * 4 + qc, xx = wx * 16 + lg * 4 + r;
      u16* dst = o_out + (size_t)((bb << 14) + yy * 128 + xx) * 192 + h * 32 + lo;
      dst[0]  = f2b(oacc[qc][0][r] * lv);
      dst[16] = f2b(oacc[qc][1][r] * lv);
    }
  }
}

// ---------------- launcher ---------------------------------------------------
extern "C" void kernel_launch(void* const* d_in, const int* in_sizes, int n_in,
                              void* d_out, int out_size, void* d_ws, size_t ws_size,
                              hipStream_t stream) {
  (void)in_sizes; (void)n_in; (void)out_size; (void)ws_size;
  const float* x      = (const float*)d_in[0];
  const float* n1g    = (const float*)d_in[1];
  const float* n1b    = (const float*)d_in[2];
  const float* qkv_w  = (const float*)d_in[3];
  const float* qkv_b  = (const float*)d_in[4];
  const float* rpb    = (const float*)d_in[5];
  const float* proj_w = (const float*)d_in[6];
  const float* proj_b = (const float*)d_in[7];
  const float* n2g    = (const float*)d_in[8];
  const float* n2b    = (const float*)d_in[9];
  const float* fc1_w  = (const float*)d_in[10];
  const float* fc1_b  = (const float*)d_in[11];
  const float* fc2_w  = (const float*)d_in[12];
  const float* fc2_b  = (const float*)d_in[13];

  char* ws = (char*)d_ws;
  u16* wq     = (u16*)(ws + 0);          // 576x192 bf16
  u16* wp     = (u16*)(ws + 221184);     // 192x192
  u16* wf1    = (u16*)(ws + 294912);     // 384x192
  u16* wf2    = (u16*)(ws + 442368);     // 192x384
  u16* biasp  = (u16*)(ws + 589824);     // packed rel-bias 1769472 B
  u16* xnbuf  = (u16*)(ws + 2359296);    // xn bf16, later attn-out o
  u16* qkvbuf = (u16*)(ws + 27525120);   // qkv bf16 (75.5MB), later xn2
  u16* ybuf   = (u16*)(ws + 52690944);   // gelu(fc1) bf16
  float* x2   = (float*)(ws + 103022592);// post-proj residual fp32

  wconv_kernel<<<(110592 + 255) / 256, 256, 0, stream>>>(qkv_w, wq, 192, 576);
  wconv_kernel<<<(36864 + 255) / 256, 256, 0, stream>>>(proj_w, wp, 192, 192);
  wconv_kernel<<<(73728 + 255) / 256, 256, 0, stream>>>(fc1_w, wf1, 192, 384);
  wconv_kernel<<<(73728 + 255) / 256, 256, 0, stream>>>(fc2_w, wf2, 384, 192);
  bias_pack_kernel<<<216, 256, 0, stream>>>(rpb, biasp);

  ln_kernel<<<16384, 256, 0, stream>>>(x, n1g, n1b, xnbuf);
  gemm_kernel<576, 192, 0><<<dim3(512, 9), 256, 0, stream>>>(xnbuf, wq, qkv_b, nullptr, qkvbuf);
  attn_kernel<<<1536, 256, 0, stream>>>(qkvbuf, biasp, xnbuf);
  gemm_kernel<192, 192, 1><<<dim3(512, 3), 256, 0, stream>>>(xnbuf, wp, proj_b, x, x2);
  ln_kernel<<<16384, 256, 0, stream>>>(x2, n2g, n2b, qkvbuf);
  gemm_kernel<384, 192, 2><<<dim3(512, 6), 256, 0, stream>>>(qkvbuf, wf1, fc1_b, nullptr, ybuf);
  gemm_kernel<192, 384, 1><<<dim3(512, 3), 256, 0, stream>>>(ybuf, wf2, fc2_b, x2, (float*)d_out);
}

// Round 2
// 391.612 us; speedup vs baseline: 1.3213x; 1.3213x over previous
//
#include <hip/hip_runtime.h>

using u16    = unsigned short;
using bf16x8 = __attribute__((ext_vector_type(8))) short;
using bf16x4 = __attribute__((ext_vector_type(4))) short;
using f32x4  = __attribute__((ext_vector_type(4))) float;
using i32x4  = __attribute__((ext_vector_type(4))) int;
using i32x2  = __attribute__((ext_vector_type(2))) int;

__device__ __forceinline__ u16 f2b(float f) {
  unsigned u = __builtin_bit_cast(unsigned, f);
  u = (u + 0x7fffu + ((u >> 16) & 1u)) >> 16;
  return (u16)u;
}
__device__ __forceinline__ float b2f(u16 h) {
  return __builtin_bit_cast(float, ((unsigned)h) << 16);
}

// ---------------- weight convert + transpose: wT[n*K+k] = w[k*N+n] (bf16) ----
__global__ void wconv_kernel(const float* __restrict__ src, u16* __restrict__ dst,
                             int K, int N) {
  int idx = blockIdx.x * 256 + threadIdx.x;
  if (idx < K * N) {
    int n = idx / K, k = idx - n * K;
    dst[idx] = f2b(src[(size_t)k * N + n]);
  }
}

// ---------------- relative-bias pre-pack into per-lane fragment layout -------
// Stores bias * log2(e) (bf16) so the attn inner loop is exp2(fma(c,SC2,bb)).
// biasp[((h*36+kt)*256 + tid)*16 + qc*4 + r] = bias[h][q][k]*log2e
//   q = (tid>>6)*64 + qc*16 + (tid&15), k = kt*16 + ((tid>>4)&3)*4 + r
__global__ void bias_pack_kernel(const float* __restrict__ table, u16* __restrict__ biasp) {
  int bid = blockIdx.x;            // h*36 + kt
  int h = bid / 36, kt = bid - h * 36;
  int t = threadIdx.x;
  int l = t & 63, w = t >> 6;
  int lo = l & 15, lg = l >> 4;
  u16 out[16];
#pragma unroll
  for (int qc = 0; qc < 4; ++qc)
#pragma unroll
    for (int r = 0; r < 4; ++r) {
      int q = w * 64 + qc * 16 + lo;
      int k = kt * 16 + lg * 4 + r;
      int i = q >> 4, j = q & 15;
      int oi = k / 24, oj = k - oi * 24;
      int idx = (i - oi + 23) * 39 + (j - oj + 23);
      out[qc * 4 + r] = f2b(table[idx * 6 + h] * 1.4426950408889634f);
    }
  u16* dst = biasp + ((size_t)(bid * 256 + t)) * 16;
  *(i32x4*)dst = *(const i32x4*)out;
  *(i32x4*)(dst + 8) = *(const i32x4*)(out + 8);
}

// ---------------- LayerNorm (192 cols) fp32 -> bf16 -------------------------
__global__ __launch_bounds__(256) void ln_kernel(const float* __restrict__ xin,
                                                 const float* __restrict__ g,
                                                 const float* __restrict__ b,
                                                 u16* __restrict__ out) {
  int row = blockIdx.x * 4 + (threadIdx.x >> 6);
  int l = threadIdx.x & 63;
  const float* xr = xin + (size_t)row * 192;
  float v0 = xr[l], v1 = xr[l + 64], v2 = xr[l + 128];
  float s1 = v0 + v1 + v2;
  float s2 = v0 * v0 + v1 * v1 + v2 * v2;
#pragma unroll
  for (int off = 32; off; off >>= 1) {
    s1 += __shfl_xor(s1, off);
    s2 += __shfl_xor(s2, off);
  }
  float mu = s1 * (1.0f / 192.0f);
  float var = s2 * (1.0f / 192.0f) - mu * mu;
  float rs = rsqrtf(var + 1e-5f);
  u16* orow = out + (size_t)row * 192;
  orow[l]       = f2b((v0 - mu) * rs * g[l]       + b[l]);
  orow[l + 64]  = f2b((v1 - mu) * rs * g[l + 64]  + b[l + 64]);
  orow[l + 128] = f2b((v2 - mu) * rs * g[l + 128] + b[l + 128]);
}

// ---------------- generic bf16 GEMM: C[M][N] = A[M][K] * WT[N][K]^T ---------
// BM=128, BN=64, 4 waves (2x2), wave tile 64x32, mfma 16x16x32 bf16.
// EPI 0: out bf16 = acc+bias ; EPI 1: out fp32 = acc+bias+res ; EPI 2: bf16 gelu(acc+bias)
template <int N, int K, int EPI>
__global__ __launch_bounds__(256, 2) void gemm_kernel(
    const u16* __restrict__ A, const u16* __restrict__ WT,
    const float* __restrict__ bias, const float* __restrict__ res,
    void* __restrict__ outp) {
  __shared__ u16 As[128 * 200];
  __shared__ u16 Ws[64 * 200];
  const int t = threadIdx.x;
  const int l = t & 63, w = t >> 6;
  const int lo = l & 15, lg = l >> 4;
  const int bm0 = blockIdx.x * 128, bn0 = blockIdx.y * 64;
  const int wr = (w >> 1) * 64, wc = (w & 1) * 32;
  f32x4 acc[4][2] = {};
  for (int c0 = 0; c0 < K; c0 += 192) {
    if (c0) __syncthreads();
#pragma unroll
    for (int i = 0; i < 12; ++i) {
      int u = t + i * 256;
      int row = u / 24, cc = (u - row * 24) * 8;
      *(i32x4*)&As[row * 200 + cc] = *(const i32x4*)&A[(size_t)(bm0 + row) * K + c0 + cc];
    }
#pragma unroll
    for (int i = 0; i < 6; ++i) {
      int u = t + i * 256;
      int row = u / 24, cc = (u - row * 24) * 8;
      *(i32x4*)&Ws[row * 200 + cc] = *(const i32x4*)&WT[(size_t)(bn0 + row) * K + c0 + cc];
    }
    __syncthreads();
#pragma unroll
    for (int kk = 0; kk < 6; ++kk) {
      bf16x8 b0 = *(const bf16x8*)&Ws[(wc + lo) * 200 + kk * 32 + lg * 8];
      bf16x8 b1 = *(const bf16x8*)&Ws[(wc + 16 + lo) * 200 + kk * 32 + lg * 8];
#pragma unroll
      for (int mi = 0; mi < 4; ++mi) {
        bf16x8 a = *(const bf16x8*)&As[(wr + mi * 16 + lo) * 200 + kk * 32 + lg * 8];
        acc[mi][0] = __builtin_amdgcn_mfma_f32_16x16x32_bf16(a, b0, acc[mi][0], 0, 0, 0);
        acc[mi][1] = __builtin_amdgcn_mfma_f32_16x16x32_bf16(a, b1, acc[mi][1], 0, 0, 0);
      }
    }
  }
#pragma unroll
  for (int ni = 0; ni < 2; ++ni) {
    int n = bn0 + wc + ni * 16 + lo;
    float bs = bias[n];
#pragma unroll
    for (int mi = 0; mi < 4; ++mi)
#pragma unroll
      for (int r = 0; r < 4; ++r) {
        int m = bm0 + wr + mi * 16 + lg * 4 + r;
        float v = acc[mi][ni][r] + bs;
        if constexpr (EPI == 0) {
          ((u16*)outp)[(size_t)m * N + n] = f2b(v);
        } else if constexpr (EPI == 1) {
          ((float*)outp)[(size_t)m * N + n] = v + res[(size_t)m * N + n];
        } else {
          float gg = 0.5f * v * (1.0f + erff(v * 0.70710678118654752f));
          ((u16*)outp)[(size_t)m * N + n] = f2b(gg);
        }
      }
  }
}

// ---------------- attention: one block per (window, head) -------------------
// Single-pass softmax with no max subtraction (scores are O(1) for LN'ed
// inputs; bias pre-scaled by log2e). K in LDS [576][36] (2x ds_read_b64),
// V transposed to VT[32][596] so PV B-frags are one ds_read_b64 per d-half.
// LDS total 79616 B -> 2 blocks/CU (8 waves) for latency hiding.
#define SC2 0.25503495627f   // (1/sqrt(32)) * log2(e)
__global__ __launch_bounds__(256, 2) void attn_kernel(const u16* __restrict__ qkv,
                                                      const u16* __restrict__ biasp,
                                                      u16* __restrict__ o_out) {
  __shared__ u16 Kl[576 * 36];
  __shared__ u16 VT[32 * 596];
  const int bx = blockIdx.x;
  const int h = bx % 6;
  const int wid = bx / 6;
  const int bb = wid >> 6, wy = (wid >> 3) & 7, wx = wid & 7;
  const int t = threadIdx.x, l = t & 63, w = t >> 6;
  const int lo = l & 15, lg = l >> 4;

  // stage K (row-major, stride 36) and V (transposed, stride 596)
#pragma unroll
  for (int i2 = 0; i2 < 9; ++i2) {
    int u = t + i2 * 256;                 // 2304 units = 576 pos x 4 quarters
    int pos = u >> 2, d0 = (u & 3) * 8;
    int oi = pos / 24, oj = pos - oi * 24;
    int y = wy * 16 - 4 + oi, x = wx * 16 - 4 + oj;
    i32x4 kv = {0, 0, 0, 0};
    bf16x8 vv = {0, 0, 0, 0, 0, 0, 0, 0};
    if ((unsigned)y < 128u && (unsigned)x < 128u) {
      const u16* s = qkv + (size_t)((bb << 14) + y * 128 + x) * 576 + h * 32 + d0;
      kv = *(const i32x4*)(s + 192);
      vv = *(const bf16x8*)(s + 384);
    }
    i32x2 klo = {kv[0], kv[1]}, khi = {kv[2], kv[3]};
    *(i32x2*)&Kl[pos * 36 + d0]     = klo;
    *(i32x2*)&Kl[pos * 36 + d0 + 4] = khi;
#pragma unroll
    for (int j = 0; j < 8; ++j) VT[(d0 + j) * 596 + pos] = (u16)vv[j];
  }

  // Q fragments: B-operand layout (col = q = lo, k-dims = lg*8..+7)
  bf16x8 qf[4];
#pragma unroll
  for (int qc = 0; qc < 4; ++qc) {
    int yy = wy * 16 + w * 4 + qc, xx = wx * 16 + lo;
    qf[qc] = *(const bf16x8*)(qkv + (size_t)((bb << 14) + yy * 128 + xx) * 576 + h * 32 + lg * 8);
  }
  __syncthreads();

  // single pass: S^T = K*Q^T (C-frag lane-local in q), exp2, PV
  float ls[4] = {0.0f, 0.0f, 0.0f, 0.0f};
  f32x4 oacc[4][2] = {};
  for (int kt = 0; kt < 36; ++kt) {
    const u16* bp = biasp + ((size_t)(h * 36 + kt) * 256 + t) * 16;
    bf16x8 bb0 = *(const bf16x8*)bp;
    bf16x8 bb1 = *(const bf16x8*)(bp + 8);
    int krow = (kt * 16 + lo) * 36 + lg * 8;
    bf16x4 k0 = *(const bf16x4*)&Kl[krow];
    bf16x4 k1 = *(const bf16x4*)&Kl[krow + 4];
    bf16x8 kf = {k0[0], k0[1], k0[2], k0[3], k1[0], k1[1], k1[2], k1[3]};
    bf16x4 pa[4];
#pragma unroll
    for (int qc = 0; qc < 4; ++qc) {
      f32x4 z = {};
      f32x4 c = __builtin_amdgcn_mfma_f32_16x16x32_bf16(kf, qf[qc], z, 0, 0, 0);
      float p0 = __builtin_amdgcn_exp2f(fmaf(c[0], SC2, b2f((u16)(qc < 2 ? bb0[qc * 4 + 0] : bb1[(qc - 2) * 4 + 0]))));
      float p1 = __builtin_amdgcn_exp2f(fmaf(c[1], SC2, b2f((u16)(qc < 2 ? bb0[qc * 4 + 1] : bb1[(qc - 2) * 4 + 1]))));
      float p2 = __builtin_amdgcn_exp2f(fmaf(c[2], SC2, b2f((u16)(qc < 2 ? bb0[qc * 4 + 2] : bb1[(qc - 2) * 4 + 2]))));
      float p3 = __builtin_amdgcn_exp2f(fmaf(c[3], SC2, b2f((u16)(qc < 2 ? bb0[qc * 4 + 3] : bb1[(qc - 2) * 4 + 3]))));
      ls[qc] += (p0 + p1) + (p2 + p3);
      bf16x4 pv = {(short)f2b(p0), (short)f2b(p1), (short)f2b(p2), (short)f2b(p3)};
      pa[qc] = pv;
    }
    int vcol = kt * 16 + lg * 4;
    bf16x4 vb0 = *(const bf16x4*)&VT[lo * 596 + vcol];
    bf16x4 vb1 = *(const bf16x4*)&VT[(16 + lo) * 596 + vcol];
#pragma unroll
    for (int qc = 0; qc < 4; ++qc) {
      oacc[qc][0] = __builtin_amdgcn_mfma_f32_16x16x16bf16_1k(pa[qc], vb0, oacc[qc][0], 0, 0, 0);
      oacc[qc][1] = __builtin_amdgcn_mfma_f32_16x16x16bf16_1k(pa[qc], vb1, oacc[qc][1], 0, 0, 0);
    }
  }

  // normalize + store
#pragma unroll
  for (int qc = 0; qc < 4; ++qc) {
    float s = ls[qc];
    s += __shfl_xor(s, 16);
    s += __shfl_xor(s, 32);
    float linv = 1.0f / s;
#pragma unroll
    for (int r = 0; r < 4; ++r) {
      float lv = __shfl(linv, lg * 4 + r);
      int yy = wy * 16 + w * 4 + qc, xx = wx * 16 + lg * 4 + r;
      u16* dst = o_out + (size_t)((bb << 14) + yy * 128 + xx) * 192 + h * 32 + lo;
      dst[0]  = f2b(oacc[qc][0][r] * lv);
      dst[16] = f2b(oacc[qc][1][r] * lv);
    }
  }
}

// ---------------- launcher ---------------------------------------------------
extern "C" void kernel_launch(void* const* d_in, const int* in_sizes, int n_in,
                              void* d_out, int out_size, void* d_ws, size_t ws_size,
                              hipStream_t stream) {
  (void)in_sizes; (void)n_in; (void)out_size; (void)ws_size;
  const float* x      = (const float*)d_in[0];
  const float* n1g    = (const float*)d_in[1];
  const float* n1b    = (const float*)d_in[2];
  const float* qkv_w  = (const float*)d_in[3];
  const float* qkv_b  = (const float*)d_in[4];
  const float* rpb    = (const float*)d_in[5];
  const float* proj_w = (const float*)d_in[6];
  const float* proj_b = (const float*)d_in[7];
  const float* n2g    = (const float*)d_in[8];
  const float* n2b    = (const float*)d_in[9];
  const float* fc1_w  = (const float*)d_in[10];
  const float* fc1_b  = (const float*)d_in[11];
  const float* fc2_w  = (const float*)d_in[12];
  const float* fc2_b  = (const float*)d_in[13];

  char* ws = (char*)d_ws;
  u16* wq     = (u16*)(ws + 0);          // 576x192 bf16
  u16* wp     = (u16*)(ws + 221184);     // 192x192
  u16* wf1    = (u16*)(ws + 294912);     // 384x192
  u16* wf2    = (u16*)(ws + 442368);     // 192x384
  u16* biasp  = (u16*)(ws + 589824);     // packed rel-bias 1769472 B
  u16* xnbuf  = (u16*)(ws + 2359296);    // xn bf16, later attn-out o
  u16* qkvbuf = (u16*)(ws + 27525120);   // qkv bf16 (75.5MB), later xn2
  u16* ybuf   = (u16*)(ws + 52690944);   // gelu(fc1) bf16
  float* x2   = (float*)(ws + 103022592);// post-proj residual fp32

  wconv_kernel<<<(110592 + 255) / 256, 256, 0, stream>>>(qkv_w, wq, 192, 576);
  wconv_kernel<<<(36864 + 255) / 256, 256, 0, stream>>>(proj_w, wp, 192, 192);
  wconv_kernel<<<(73728 + 255) / 256, 256, 0, stream>>>(fc1_w, wf1, 192, 384);
  wconv_kernel<<<(73728 + 255) / 256, 256, 0, stream>>>(fc2_w, wf2, 384, 192);
  bias_pack_kernel<<<216, 256, 0, stream>>>(rpb, biasp);

  ln_kernel<<<16384, 256, 0, stream>>>(x, n1g, n1b, xnbuf);
  gemm_kernel<576, 192, 0><<<dim3(512, 9), 256, 0, stream>>>(xnbuf, wq, qkv_b, nullptr, qkvbuf);
  attn_kernel<<<1536, 256, 0, stream>>>(qkvbuf, biasp, xnbuf);
  gemm_kernel<192, 192, 1><<<dim3(512, 3), 256, 0, stream>>>(xnbuf, wp, proj_b, x, x2);
  ln_kernel<<<16384, 256, 0, stream>>>(x2, n2g, n2b, qkvbuf);
  gemm_kernel<384, 192, 2><<<dim3(512, 6), 256, 0, stream>>>(qkvbuf, wf1, fc1_b, nullptr, ybuf);
  gemm_kernel<192, 384, 1><<<dim3(512, 3), 256, 0, stream>>>(ybuf, wf2, fc2_b, x2, (float*)d_out);
}

// Round 3
// 378.139 us; speedup vs baseline: 1.3683x; 1.0356x over previous
//
#include <hip/hip_runtime.h>

using u16    = unsigned short;
using bf16x8 = __attribute__((ext_vector_type(8))) short;
using bf16x4 = __attribute__((ext_vector_type(4))) short;
using f32x4  = __attribute__((ext_vector_type(4))) float;
using i32x4  = __attribute__((ext_vector_type(4))) int;
using i32x2  = __attribute__((ext_vector_type(2))) int;

#define QSCALE 0.2550351115f   // (1/sqrt(32)) * log2(e)
#define LOG2E  1.4426950408889634f

__device__ __forceinline__ u16 f2b(float f) {
  unsigned u = __builtin_bit_cast(unsigned, f);
  u = (u + 0x7fffu + ((u >> 16) & 1u)) >> 16;
  return (u16)u;
}
__device__ __forceinline__ float b2f(u16 h) {
  return __builtin_bit_cast(float, ((unsigned)h) << 16);
}
__device__ __forceinline__ int cvt_pk(float a, float b) {
  int r;
  asm("v_cvt_pk_bf16_f32 %0, %1, %2" : "=v"(r) : "v"(a), "v"(b));
  return r;
}
__device__ __forceinline__ void gload_lds16(const u16* g, u16* l) {
  __builtin_amdgcn_global_load_lds(
      (const __attribute__((address_space(1))) unsigned int*)(g),
      (__attribute__((address_space(3))) unsigned int*)(l), 16, 0, 0);
}

// ---------------- weight transpose f32 -> bf16, LDS-tiled, coalesced both sides
__global__ __launch_bounds__(256) void wconv_kernel(const float* __restrict__ src,
                                                    u16* __restrict__ dst, int K, int N) {
  __shared__ u16 tile[32][33];
  int kb = blockIdx.x * 32, nb = blockIdx.y * 32;
  int tx = threadIdx.x & 31, ty = threadIdx.x >> 5;   // 32 x 8
#pragma unroll
  for (int r = 0; r < 32; r += 8)
    tile[ty + r][tx] = f2b(src[(size_t)(kb + ty + r) * N + nb + tx]);
  __syncthreads();
#pragma unroll
  for (int r = 0; r < 32; r += 8)
    dst[(size_t)(nb + ty + r) * K + kb + tx] = tile[tx][ty + r];
}

// ---------------- relative-bias pre-pack: f32 * log2e, C-fragment order ------
// biaspf[((h*36+kt)*256 + tid)*16 + qc*4 + r] = bias[h][q][k]*log2e (f32)
//   q = (tid>>6)*64 + qc*16 + (tid&15), k = kt*16 + ((tid>>4)&3)*4 + r
__global__ void bias_pack_kernel(const float* __restrict__ table, float* __restrict__ biaspf) {
  int bid = blockIdx.x;            // h*36 + kt
  int h = bid / 36, kt = bid - h * 36;
  int t = threadIdx.x;
  int l = t & 63, w = t >> 6;
  int lo = l & 15, lg = l >> 4;
  float out[16];
#pragma unroll
  for (int qc = 0; qc < 4; ++qc)
#pragma unroll
    for (int r = 0; r < 4; ++r) {
      int q = w * 64 + qc * 16 + lo;
      int k = kt * 16 + lg * 4 + r;
      int i = q >> 4, j = q & 15;
      int oi = k / 24, oj = k - oi * 24;
      int idx = (i - oi + 23) * 39 + (j - oj + 23);
      out[qc * 4 + r] = table[idx * 6 + h] * LOG2E;
    }
  float* dst = biaspf + ((size_t)(bid * 256 + t)) * 16;
#pragma unroll
  for (int v = 0; v < 4; ++v) *(f32x4*)(dst + v * 4) = *(const f32x4*)(out + v * 4);
}

// ---------------- LayerNorm (192 cols) -> bf16, templated input type --------
template <typename TI>
__global__ __launch_bounds__(256) void ln_kernel(const TI* __restrict__ xin,
                                                 const float* __restrict__ g,
                                                 const float* __restrict__ b,
                                                 u16* __restrict__ out) {
  int row = blockIdx.x * 4 + (threadIdx.x >> 6);
  int l = threadIdx.x & 63;
  const TI* xr = xin + (size_t)row * 192;
  float v0, v1, v2;
  if constexpr (sizeof(TI) == 2) {
    v0 = b2f(xr[l]); v1 = b2f(xr[l + 64]); v2 = b2f(xr[l + 128]);
  } else {
    v0 = xr[l]; v1 = xr[l + 64]; v2 = xr[l + 128];
  }
  float s1 = v0 + v1 + v2;
  float s2 = v0 * v0 + v1 * v1 + v2 * v2;
#pragma unroll
  for (int off = 32; off; off >>= 1) {
    s1 += __shfl_xor(s1, off);
    s2 += __shfl_xor(s2, off);
  }
  float mu = s1 * (1.0f / 192.0f);
  float var = s2 * (1.0f / 192.0f) - mu * mu;
  float rs = rsqrtf(var + 1e-5f);
  u16* orow = out + (size_t)row * 192;
  orow[l]       = f2b((v0 - mu) * rs * g[l]       + b[l]);
  orow[l + 64]  = f2b((v1 - mu) * rs * g[l + 64]  + b[l + 64]);
  orow[l + 128] = f2b((v2 - mu) * rs * g[l + 128] + b[l + 128]);
}

// ---------------- generic bf16 GEMM: C[M][N] = A[M][K] * WT[N][K]^T ---------
// BM=128, BN=64, 4 waves (2x2), wave tile 64x32, mfma 16x16x32 bf16.
// Staging via global_load_lds (16B), XOR-swizzled within 8-chunk groups.
// EPI 2: bf16 gelu(acc+bias); EPI 3: bf16 (acc+bias)*(n<192?QSCALE:1);
// EPI 4: bf16 acc+bias+res_f32; EPI 5: f32 acc+bias+res_bf16.
template <int N, int K, int EPI>
__global__ __launch_bounds__(256, 2) void gemm_kernel(
    const u16* __restrict__ A, const u16* __restrict__ WT,
    const float* __restrict__ bias, const void* __restrict__ res,
    void* __restrict__ outp) {
  __shared__ u16 As[128 * 192];
  __shared__ u16 Ws[64 * 192];
  const int t = threadIdx.x;
  const int l = t & 63, w = t >> 6;
  const int lo = l & 15, lg = l >> 4;
  const int bm0 = blockIdx.x * 128, bn0 = blockIdx.y * 64;
  const int wr = (w >> 1) * 64, wc = (w & 1) * 32;
  f32x4 acc[4][2] = {};
  for (int c0 = 0; c0 < K; c0 += 192) {
    if (c0) __syncthreads();
    // A: 3072 16B-units, unit u at LDS As[u*8]; global chunk xor-swizzled
#pragma unroll
    for (int i = 0; i < 12; ++i) {
      int u = t + i * 256;
      int row = u / 24, ch = u - row * 24;
      int cg = (ch & ~7) | ((ch ^ row) & 7);
      gload_lds16(&A[(size_t)(bm0 + row) * K + c0 + cg * 8], &As[u * 8]);
    }
#pragma unroll
    for (int i = 0; i < 6; ++i) {
      int u = t + i * 256;
      int row = u / 24, ch = u - row * 24;
      int cg = (ch & ~7) | ((ch ^ row) & 7);
      gload_lds16(&WT[(size_t)(bn0 + row) * K + c0 + cg * 8], &Ws[u * 8]);
    }
    __syncthreads();
#pragma unroll
    for (int kk = 0; kk < 6; ++kk) {
      int cb = kk * 4 + lg;
      int cofs = ((cb & ~7) | ((cb ^ lo) & 7)) * 8;   // rows of all frags == lo (mod 8)
      bf16x8 b0 = *(const bf16x8*)&Ws[(wc + lo) * 192 + cofs];
      bf16x8 b1 = *(const bf16x8*)&Ws[(wc + 16 + lo) * 192 + cofs];
#pragma unroll
      for (int mi = 0; mi < 4; ++mi) {
        bf16x8 a = *(const bf16x8*)&As[(wr + mi * 16 + lo) * 192 + cofs];
        acc[mi][0] = __builtin_amdgcn_mfma_f32_16x16x32_bf16(a, b0, acc[mi][0], 0, 0, 0);
        acc[mi][1] = __builtin_amdgcn_mfma_f32_16x16x32_bf16(a, b1, acc[mi][1], 0, 0, 0);
      }
    }
  }
#pragma unroll
  for (int ni = 0; ni < 2; ++ni) {
    int n = bn0 + wc + ni * 16 + lo;
    float bs = bias[n];
#pragma unroll
    for (int mi = 0; mi < 4; ++mi)
#pragma unroll
      for (int r = 0; r < 4; ++r) {
        int m = bm0 + wr + mi * 16 + lg * 4 + r;
        float v = acc[mi][ni][r] + bs;
        size_t idx = (size_t)m * N + n;
        if constexpr (EPI == 2) {
          float gg = 0.5f * v * (1.0f + erff(v * 0.70710678118654752f));
          ((u16*)outp)[idx] = f2b(gg);
        } else if constexpr (EPI == 3) {
          float sc = (n < 192) ? QSCALE : 1.0f;
          ((u16*)outp)[idx] = f2b(v * sc);
        } else if constexpr (EPI == 4) {
          ((u16*)outp)[idx] = f2b(v + ((const float*)res)[idx]);
        } else {
          ((float*)outp)[idx] = v + b2f(((const u16*)res)[idx]);
        }
      }
  }
}

// ---------------- attention: one block per (window, head) -------------------
// Q pre-scaled by QSCALE (qkv-GEMM epilogue); bias pre-scaled by log2e and fed
// as the QK^T MFMA C-operand -> score*log2e lands directly in the C-frag.
// p = exp2(c); packed to bf16 via v_cvt_pk_bf16_f32; PV as 16x16x32 over
// kt-pairs with sigma-permuted V slots so A/B slot maps agree.
__global__ __launch_bounds__(256, 2) void attn_kernel(const u16* __restrict__ qkv,
                                                      const float* __restrict__ biaspf,
                                                      u16* __restrict__ o_out) {
  __shared__ u16 Kl[576 * 36];
  __shared__ u16 VT[32 * 600];
  const int bx = blockIdx.x;
  const int h = bx % 6;
  const int wid = bx / 6;
  const int bb = wid >> 6, wy = (wid >> 3) & 7, wx = wid & 7;
  const int t = threadIdx.x, l = t & 63, w = t >> 6;
  const int lo = l & 15, lg = l >> 4;

  // stage K (row-major, stride 36) and V (transposed + sigma slot permute)
#pragma unroll
  for (int i2 = 0; i2 < 9; ++i2) {
    int u = t + i2 * 256;                 // 2304 units = 576 pos x 4 quarters
    int pos = u >> 2, d0 = (u & 3) * 8;
    int oi = pos / 24, oj = pos - oi * 24;
    int y = wy * 16 - 4 + oi, x = wx * 16 - 4 + oj;
    i32x4 kv = {0, 0, 0, 0};
    bf16x8 vv = {0, 0, 0, 0, 0, 0, 0, 0};
    if ((unsigned)y < 128u && (unsigned)x < 128u) {
      const u16* s = qkv + (size_t)((bb << 14) + y * 128 + x) * 576 + h * 32 + d0;
      kv = *(const i32x4*)(s + 192);
      vv = *(const bf16x8*)(s + 384);
    }
    i32x2 klo = {kv[0], kv[1]}, khi = {kv[2], kv[3]};
    *(i32x2*)&Kl[pos * 36 + d0]     = klo;
    *(i32x2*)&Kl[pos * 36 + d0 + 4] = khi;
    // sigma: slot = ((pos>>2)&3)*8 + ((pos>>4)&1)*4 + (pos&3) within each 32-block
    int p5 = pos & 31;
    int spos = (pos & ~31) | (((p5 >> 2) & 3) << 3) | (((p5 >> 4) & 1) << 2) | (p5 & 3);
#pragma unroll
    for (int j = 0; j < 8; ++j) VT[(d0 + j) * 600 + spos] = (u16)vv[j];
  }

  // Q fragments: B-operand layout (col = q = lo, k-dims = lg*8..+7)
  bf16x8 qf[4];
#pragma unroll
  for (int qc = 0; qc < 4; ++qc) {
    int yy = wy * 16 + w * 4 + qc, xx = wx * 16 + lo;
    qf[qc] = *(const bf16x8*)(qkv + (size_t)((bb << 14) + yy * 128 + xx) * 576 + h * 32 + lg * 8);
  }
  __syncthreads();

  float ls[4] = {0.0f, 0.0f, 0.0f, 0.0f};
  f32x4 oacc[4][2] = {};
  const float* bbase = biaspf + ((size_t)(h * 36) * 256 + t) * 16;
  for (int kt2 = 0; kt2 < 18; ++kt2) {
    i32x4 pw[4];
#pragma unroll
    for (int hf = 0; hf < 2; ++hf) {
      int kt = kt2 * 2 + hf;
      const f32x4* bp = (const f32x4*)(bbase + (size_t)kt * 4096);
      int krow = (kt * 16 + lo) * 36 + lg * 8;
      bf16x4 k0 = *(const bf16x4*)&Kl[krow];
      bf16x4 k1 = *(const bf16x4*)&Kl[krow + 4];
      bf16x8 kf = {k0[0], k0[1], k0[2], k0[3], k1[0], k1[1], k1[2], k1[3]};
#pragma unroll
      for (int qc = 0; qc < 4; ++qc) {
        f32x4 c = __builtin_amdgcn_mfma_f32_16x16x32_bf16(kf, qf[qc], bp[qc], 0, 0, 0);
        float p0 = __builtin_amdgcn_exp2f(c[0]);
        float p1 = __builtin_amdgcn_exp2f(c[1]);
        float p2 = __builtin_amdgcn_exp2f(c[2]);
        float p3 = __builtin_amdgcn_exp2f(c[3]);
        ls[qc] += (p0 + p1) + (p2 + p3);
        pw[qc][hf * 2 + 0] = cvt_pk(p0, p1);
        pw[qc][hf * 2 + 1] = cvt_pk(p2, p3);
      }
    }
    int vofs = kt2 * 32 + lg * 8;
    bf16x8 vb0 = *(const bf16x8*)&VT[lo * 600 + vofs];
    bf16x8 vb1 = *(const bf16x8*)&VT[(16 + lo) * 600 + vofs];
#pragma unroll
    for (int qc = 0; qc < 4; ++qc) {
      bf16x8 pa = __builtin_bit_cast(bf16x8, pw[qc]);
      oacc[qc][0] = __builtin_amdgcn_mfma_f32_16x16x32_bf16(pa, vb0, oacc[qc][0], 0, 0, 0);
      oacc[qc][1] = __builtin_amdgcn_mfma_f32_16x16x32_bf16(pa, vb1, oacc[qc][1], 0, 0, 0);
    }
  }

  // normalize + store
#pragma unroll
  for (int qc = 0; qc < 4; ++qc) {
    float s = ls[qc];
    s += __shfl_xor(s, 16);
    s += __shfl_xor(s, 32);
    float linv = 1.0f / s;
#pragma unroll
    for (int r = 0; r < 4; ++r) {
      float lv = __shfl(linv, lg * 4 + r);
      int yy = wy * 16 + w * 4 + qc, xx = wx * 16 + lg * 4 + r;
      u16* dst = o_out + (size_t)((bb << 14) + yy * 128 + xx) * 192 + h * 32 + lo;
      dst[0]  = f2b(oacc[qc][0][r] * lv);
      dst[16] = f2b(oacc[qc][1][r] * lv);
    }
  }
}

// ---------------- launcher ---------------------------------------------------
extern "C" void kernel_launch(void* const* d_in, const int* in_sizes, int n_in,
                              void* d_out, int out_size, void* d_ws, size_t ws_size,
                              hipStream_t stream) {
  (void)in_sizes; (void)n_in; (void)out_size; (void)ws_size;
  const float* x      = (const float*)d_in[0];
  const float* n1g    = (const float*)d_in[1];
  const float* n1b    = (const float*)d_in[2];
  const float* qkv_w  = (const float*)d_in[3];
  const float* qkv_b  = (const float*)d_in[4];
  const float* rpb    = (const float*)d_in[5];
  const float* proj_w = (const float*)d_in[6];
  const float* proj_b = (const float*)d_in[7];
  const float* n2g    = (const float*)d_in[8];
  const float* n2b    = (const float*)d_in[9];
  const float* fc1_w  = (const float*)d_in[10];
  const float* fc1_b  = (const float*)d_in[11];
  const float* fc2_w  = (const float*)d_in[12];
  const float* fc2_b  = (const float*)d_in[13];

  char* ws = (char*)d_ws;
  u16*   wq     = (u16*)(ws + 0);          // 576x192 bf16
  u16*   wp     = (u16*)(ws + 221184);     // 192x192
  u16*   wf1    = (u16*)(ws + 294912);     // 384x192
  u16*   wf2    = (u16*)(ws + 442368);     // 192x384
  float* biaspf = (float*)(ws + 589824);   // packed rel-bias f32, 3538944 B
  u16*   xnbuf  = (u16*)(ws + 4194304);    // xn bf16 (25MB), later attn-out o
  u16*   qkvbuf = (u16*)(ws + 29360128);   // qkv bf16 (75.5MB); later xn2 (first 25MB)
  u16*   ybuf   = (u16*)(ws + 54525952);   // gelu(fc1) bf16 (50MB), inside old qkv region
  u16*   x2     = (u16*)(ws + 104857600);  // post-proj residual bf16 (25MB)

  wconv_kernel<<<dim3(6, 18), 256, 0, stream>>>(qkv_w, wq, 192, 576);
  wconv_kernel<<<dim3(6, 6),  256, 0, stream>>>(proj_w, wp, 192, 192);
  wconv_kernel<<<dim3(6, 12), 256, 0, stream>>>(fc1_w, wf1, 192, 384);
  wconv_kernel<<<dim3(12, 6), 256, 0, stream>>>(fc2_w, wf2, 384, 192);
  bias_pack_kernel<<<216, 256, 0, stream>>>(rpb, biaspf);

  ln_kernel<float><<<16384, 256, 0, stream>>>(x, n1g, n1b, xnbuf);
  gemm_kernel<576, 192, 3><<<dim3(512, 9), 256, 0, stream>>>(xnbuf, wq, qkv_b, nullptr, qkvbuf);
  attn_kernel<<<1536, 256, 0, stream>>>(qkvbuf, biaspf, xnbuf);
  gemm_kernel<192, 192, 4><<<dim3(512, 3), 256, 0, stream>>>(xnbuf, wp, proj_b, x, x2);
  ln_kernel<u16><<<16384, 256, 0, stream>>>(x2, n2g, n2b, qkvbuf);
  gemm_kernel<384, 192, 2><<<dim3(512, 6), 256, 0, stream>>>(qkvbuf, wf1, fc1_b, nullptr, ybuf);
  gemm_kernel<192, 384, 5><<<dim3(512, 3), 256, 0, stream>>>(ybuf, wf2, fc2_b, x2, (float*)d_out);
}

// Round 4
// 354.373 us; speedup vs baseline: 1.4601x; 1.0671x over previous
//
#include <hip/hip_runtime.h>

using u16    = unsigned short;
using bf16x8 = __attribute__((ext_vector_type(8))) short;
using bf16x4 = __attribute__((ext_vector_type(4))) short;
using f32x4  = __attribute__((ext_vector_type(4))) float;
using i32x4  = __attribute__((ext_vector_type(4))) int;
using i32x2  = __attribute__((ext_vector_type(2))) int;

#define QSCALE 0.2550351115f   // (1/sqrt(32)) * log2(e)
#define LOG2E  1.4426950408889634f

__device__ __forceinline__ u16 f2b(float f) {
  unsigned u = __builtin_bit_cast(unsigned, f);
  u = (u + 0x7fffu + ((u >> 16) & 1u)) >> 16;
  return (u16)u;
}
__device__ __forceinline__ float b2f(u16 h) {
  return __builtin_bit_cast(float, ((unsigned)h) << 16);
}
__device__ __forceinline__ int cvt_pk(float a, float b) {
  int r;
  asm("v_cvt_pk_bf16_f32 %0, %1, %2" : "=v"(r) : "v"(a), "v"(b));
  return r;
}
__device__ __forceinline__ void gload_lds16(const u16* g, u16* l) {
  __builtin_amdgcn_global_load_lds(
      (const __attribute__((address_space(1))) unsigned int*)(g),
      (__attribute__((address_space(3))) unsigned int*)(l), 16, 0, 0);
}

// ---------------- weight transpose f32 -> bf16, LDS-tiled, coalesced both sides
__global__ __launch_bounds__(256) void wconv_kernel(const float* __restrict__ src,
                                                    u16* __restrict__ dst, int K, int N) {
  __shared__ u16 tile[32][33];
  int kb = blockIdx.x * 32, nb = blockIdx.y * 32;
  int tx = threadIdx.x & 31, ty = threadIdx.x >> 5;   // 32 x 8
#pragma unroll
  for (int r = 0; r < 32; r += 8)
    tile[ty + r][tx] = f2b(src[(size_t)(kb + ty + r) * N + nb + tx]);
  __syncthreads();
#pragma unroll
  for (int r = 0; r < 32; r += 8)
    dst[(size_t)(nb + ty + r) * K + kb + tx] = tile[tx][ty + r];
}

// ---------------- relative-bias pre-pack: f32 * log2e, C-fragment order ------
// 512-thread layout: biaspf[((h*36+kt)*512 + t)*8 + qc*4 + r]
//   q = (t>>6)*32 + qc*16 + (t&15), k = kt*16 + ((t>>4)&3)*4 + r
__global__ void bias_pack_kernel(const float* __restrict__ table, float* __restrict__ biaspf) {
  int bid = blockIdx.x;            // h*36 + kt
  int h = bid / 36, kt = bid - h * 36;
  int t = threadIdx.x;
  int w = t >> 6, lo = t & 15, lg = (t >> 4) & 3;
  float out[8];
#pragma unroll
  for (int qc = 0; qc < 2; ++qc)
#pragma unroll
    for (int r = 0; r < 4; ++r) {
      int q = w * 32 + qc * 16 + lo;
      int k = kt * 16 + lg * 4 + r;
      int i = q >> 4, j = q & 15;
      int oi = k / 24, oj = k - oi * 24;
      int idx = (i - oi + 23) * 39 + (j - oj + 23);
      out[qc * 4 + r] = table[idx * 6 + h] * LOG2E;
    }
  float* dst = biaspf + ((size_t)(bid * 512 + t)) * 8;
  *(f32x4*)dst       = *(const f32x4*)out;
  *(f32x4*)(dst + 4) = *(const f32x4*)(out + 4);
}

// ---------------- LayerNorm (192 cols) -> bf16, templated input type --------
template <typename TI>
__global__ __launch_bounds__(256) void ln_kernel(const TI* __restrict__ xin,
                                                 const float* __restrict__ g,
                                                 const float* __restrict__ b,
                                                 u16* __restrict__ out) {
  int row = blockIdx.x * 4 + (threadIdx.x >> 6);
  int l = threadIdx.x & 63;
  const TI* xr = xin + (size_t)row * 192;
  float v0, v1, v2;
  if constexpr (sizeof(TI) == 2) {
    v0 = b2f(xr[l]); v1 = b2f(xr[l + 64]); v2 = b2f(xr[l + 128]);
  } else {
    v0 = xr[l]; v1 = xr[l + 64]; v2 = xr[l + 128];
  }
  float s1 = v0 + v1 + v2;
  float s2 = v0 * v0 + v1 * v1 + v2 * v2;
#pragma unroll
  for (int off = 32; off; off >>= 1) {
    s1 += __shfl_xor(s1, off);
    s2 += __shfl_xor(s2, off);
  }
  float mu = s1 * (1.0f / 192.0f);
  float var = s2 * (1.0f / 192.0f) - mu * mu;
  float rs = rsqrtf(var + 1e-5f);
  u16* orow = out + (size_t)row * 192;
  orow[l]       = f2b((v0 - mu) * rs * g[l]       + b[l]);
  orow[l + 64]  = f2b((v1 - mu) * rs * g[l + 64]  + b[l + 64]);
  orow[l + 128] = f2b((v2 - mu) * rs * g[l + 128] + b[l + 128]);
}

// ---------------- generic bf16 GEMM: C[M][N] = A[M][K] * WT[N][K]^T ---------
// BM=128, BN=64, 4 waves (2x2), wave tile 64x32, mfma 16x16x32 bf16.
// Staging via global_load_lds (16B), XOR-swizzled within 8-chunk groups.
// EPI 2: bf16 gelu(acc+bias); EPI 3: bf16 (acc+bias)*(n<192?QSCALE:1);
// EPI 4: bf16 acc+bias+res_f32; EPI 5: f32 acc+bias+res_bf16.
template <int N, int K, int EPI>
__global__ __launch_bounds__(256, 2) void gemm_kernel(
    const u16* __restrict__ A, const u16* __restrict__ WT,
    const float* __restrict__ bias, const void* __restrict__ res,
    void* __restrict__ outp) {
  __shared__ u16 As[128 * 192];
  __shared__ u16 Ws[64 * 192];
  const int t = threadIdx.x;
  const int l = t & 63, w = t >> 6;
  const int lo = l & 15, lg = l >> 4;
  const int bm0 = blockIdx.x * 128, bn0 = blockIdx.y * 64;
  const int wr = (w >> 1) * 64, wc = (w & 1) * 32;
  f32x4 acc[4][2] = {};
  for (int c0 = 0; c0 < K; c0 += 192) {
    if (c0) __syncthreads();
    // A: 3072 16B-units, unit u at LDS As[u*8]; global chunk xor-swizzled
#pragma unroll
    for (int i = 0; i < 12; ++i) {
      int u = t + i * 256;
      int row = u / 24, ch = u - row * 24;
      int cg = (ch & ~7) | ((ch ^ row) & 7);
      gload_lds16(&A[(size_t)(bm0 + row) * K + c0 + cg * 8], &As[u * 8]);
    }
#pragma unroll
    for (int i = 0; i < 6; ++i) {
      int u = t + i * 256;
      int row = u / 24, ch = u - row * 24;
      int cg = (ch & ~7) | ((ch ^ row) & 7);
      gload_lds16(&WT[(size_t)(bn0 + row) * K + c0 + cg * 8], &Ws[u * 8]);
    }
    __syncthreads();
#pragma unroll
    for (int kk = 0; kk < 6; ++kk) {
      int cb = kk * 4 + lg;
      int cofs = ((cb & ~7) | ((cb ^ lo) & 7)) * 8;   // rows of all frags == lo (mod 8)
      bf16x8 b0 = *(const bf16x8*)&Ws[(wc + lo) * 192 + cofs];
      bf16x8 b1 = *(const bf16x8*)&Ws[(wc + 16 + lo) * 192 + cofs];
#pragma unroll
      for (int mi = 0; mi < 4; ++mi) {
        bf16x8 a = *(const bf16x8*)&As[(wr + mi * 16 + lo) * 192 + cofs];
        acc[mi][0] = __builtin_amdgcn_mfma_f32_16x16x32_bf16(a, b0, acc[mi][0], 0, 0, 0);
        acc[mi][1] = __builtin_amdgcn_mfma_f32_16x16x32_bf16(a, b1, acc[mi][1], 0, 0, 0);
      }
    }
  }
#pragma unroll
  for (int ni = 0; ni < 2; ++ni) {
    int n = bn0 + wc + ni * 16 + lo;
    float bs = bias[n];
#pragma unroll
    for (int mi = 0; mi < 4; ++mi)
#pragma unroll
      for (int r = 0; r < 4; ++r) {
        int m = bm0 + wr + mi * 16 + lg * 4 + r;
        float v = acc[mi][ni][r] + bs;
        size_t idx = (size_t)m * N + n;
        if constexpr (EPI == 2) {
          float gg = 0.5f * v * (1.0f + erff(v * 0.70710678118654752f));
          ((u16*)outp)[idx] = f2b(gg);
        } else if constexpr (EPI == 3) {
          float sc = (n < 192) ? QSCALE : 1.0f;
          ((u16*)outp)[idx] = f2b(v * sc);
        } else if constexpr (EPI == 4) {
          ((u16*)outp)[idx] = f2b(v + ((const float*)res)[idx]);
        } else {
          ((float*)outp)[idx] = v + b2f(((const u16*)res)[idx]);
        }
      }
  }
}

// ---------------- attention: one 512-thread block per (window, head) --------
// 8 waves x 32 q-rows. Q pre-scaled by QSCALE; bias (f32, *log2e) is the QK^T
// MFMA C-operand, register-double-buffered one kt-pair ahead. p = exp2(c),
// packed via v_cvt_pk_bf16_f32; PV as 16x16x32 over kt-pairs with
// sigma-permuted + row-XOR-swizzled V slots (conflict-free staging).
__global__ __launch_bounds__(512, 4) void attn_kernel(const u16* __restrict__ qkv,
                                                      const float* __restrict__ biaspf,
                                                      u16* __restrict__ o_out) {
  __shared__ u16 Kl[576 * 36];
  __shared__ u16 VT[32 * 600];
  const int bx = blockIdx.x;
  const int h = bx % 6;
  const int wid = bx / 6;
  const int bb = wid >> 6, wy = (wid >> 3) & 7, wx = wid & 7;
  const int t = threadIdx.x;
  const int w = t >> 6, lo = t & 15, lg = (t >> 4) & 3;

  // stage K (row-major, stride 36) and V (transposed, sigma slot permute +
  // row-XOR bank swizzle)
#pragma unroll
  for (int i2 = 0; i2 < 5; ++i2) {
    int u = t + i2 * 512;                 // 2304 units = 576 pos x 4 quarters
    if (u < 2304) {
      int pos = u >> 2, d0 = (u & 3) * 8;
      int oi = pos / 24, oj = pos - oi * 24;
      int y = wy * 16 - 4 + oi, x = wx * 16 - 4 + oj;
      i32x4 kv = {0, 0, 0, 0};
      bf16x8 vv = {0, 0, 0, 0, 0, 0, 0, 0};
      if ((unsigned)y < 128u && (unsigned)x < 128u) {
        const u16* s = qkv + (size_t)((bb << 14) + y * 128 + x) * 576 + h * 32 + d0;
        kv = *(const i32x4*)(s + 192);
        vv = *(const bf16x8*)(s + 384);
      }
      i32x2 klo = {kv[0], kv[1]}, khi = {kv[2], kv[3]};
      *(i32x2*)&Kl[pos * 36 + d0]     = klo;
      *(i32x2*)&Kl[pos * 36 + d0 + 4] = khi;
      // sigma: slot = ((pos>>2)&3)*8 + ((pos>>4)&1)*4 + (pos&3) within 32-block
      int p5 = pos & 31;
      int slot = (((p5 >> 2) & 3) << 3) | (((p5 >> 4) & 1) << 2) | (p5 & 3);
      int base = (pos & ~31);
#pragma unroll
      for (int j = 0; j < 8; ++j) {
        int row = d0 + j;
        int scol = (slot & 7) | ((((slot >> 3) ^ (row >> 3)) & 3) << 3);
        VT[row * 600 + base + scol] = (u16)vv[j];
      }
    }
  }

  // Q fragments: B-operand layout (col = q = lo, k-dims = lg*8..+7)
  bf16x8 qf[2];
#pragma unroll
  for (int qc = 0; qc < 2; ++qc) {
    int yy = wy * 16 + w * 2 + qc, xx = wx * 16 + lo;
    qf[qc] = *(const bf16x8*)(qkv + (size_t)((bb << 14) + yy * 128 + xx) * 576 + h * 32 + lg * 8);
  }
  __syncthreads();

  float ls[2] = {0.0f, 0.0f};
  f32x4 oacc[2][2] = {};
  const f32x4* bbase = (const f32x4*)(biaspf + ((size_t)(h * 36) * 512 + t) * 8);
  // bbase stride per kt = 512*8 floats = 1024 f32x4
  f32x4 bc[4];   // current pair bias: [hf*2+qc]
#pragma unroll
  for (int i = 0; i < 4; ++i) bc[i] = bbase[(i >> 1) * 1024 + (i & 1)];
  const int xr0 = lo >> 3, xr1 = 2 | (lo >> 3);

  for (int kt2 = 0; kt2 < 18; ++kt2) {
    // prefetch next kt-pair's bias (clamped on last iteration)
    int ktn = (kt2 < 17) ? (kt2 + 1) : 17;
    f32x4 bn[4];
#pragma unroll
    for (int i = 0; i < 4; ++i) bn[i] = bbase[(2 * ktn + (i >> 1)) * 1024 + (i & 1)];

    i32x4 pw[2];
#pragma unroll
    for (int hf = 0; hf < 2; ++hf) {
      int kt = kt2 * 2 + hf;
      int krow = (kt * 16 + lo) * 36 + lg * 8;
      bf16x4 k0 = *(const bf16x4*)&Kl[krow];
      bf16x4 k1 = *(const bf16x4*)&Kl[krow + 4];
      bf16x8 kf = {k0[0], k0[1], k0[2], k0[3], k1[0], k1[1], k1[2], k1[3]};
#pragma unroll
      for (int qc = 0; qc < 2; ++qc) {
        f32x4 c = __builtin_amdgcn_mfma_f32_16x16x32_bf16(kf, qf[qc], bc[hf * 2 + qc], 0, 0, 0);
        float p0 = __builtin_amdgcn_exp2f(c[0]);
        float p1 = __builtin_amdgcn_exp2f(c[1]);
        float p2 = __builtin_amdgcn_exp2f(c[2]);
        float p3 = __builtin_amdgcn_exp2f(c[3]);
        ls[qc] += (p0 + p1) + (p2 + p3);
        pw[qc][hf * 2 + 0] = cvt_pk(p0, p1);
        pw[qc][hf * 2 + 1] = cvt_pk(p2, p3);
      }
    }
    int vb = kt2 * 32;
    bf16x8 vb0 = *(const bf16x8*)&VT[lo * 600 + vb + ((lg ^ xr0) & 3) * 8];
    bf16x8 vb1 = *(const bf16x8*)&VT[(16 + lo) * 600 + vb + ((lg ^ xr1) & 3) * 8];
#pragma unroll
    for (int qc = 0; qc < 2; ++qc) {
      bf16x8 pa = __builtin_bit_cast(bf16x8, pw[qc]);
      oacc[qc][0] = __builtin_amdgcn_mfma_f32_16x16x32_bf16(pa, vb0, oacc[qc][0], 0, 0, 0);
      oacc[qc][1] = __builtin_amdgcn_mfma_f32_16x16x32_bf16(pa, vb1, oacc[qc][1], 0, 0, 0);
    }
#pragma unroll
    for (int i = 0; i < 4; ++i) bc[i] = bn[i];
  }

  // normalize + store
#pragma unroll
  for (int qc = 0; qc < 2; ++qc) {
    float s = ls[qc];
    s += __shfl_xor(s, 16);
    s += __shfl_xor(s, 32);
    float linv = 1.0f / s;
#pragma unroll
    for (int r = 0; r < 4; ++r) {
      float lv = __shfl(linv, lg * 4 + r);
      int yy = wy * 16 + w * 2 + qc, xx = wx * 16 + lg * 4 + r;
      u16* dst = o_out + (size_t)((bb << 14) + yy * 128 + xx) * 192 + h * 32 + lo;
      dst[0]  = f2b(oacc[qc][0][r] * lv);
      dst[16] = f2b(oacc[qc][1][r] * lv);
    }
  }
}

// ---------------- launcher ---------------------------------------------------
extern "C" void kernel_launch(void* const* d_in, const int* in_sizes, int n_in,
                              void* d_out, int out_size, void* d_ws, size_t ws_size,
                              hipStream_t stream) {
  (void)in_sizes; (void)n_in; (void)out_size; (void)ws_size;
  const float* x      = (const float*)d_in[0];
  const float* n1g    = (const float*)d_in[1];
  const float* n1b    = (const float*)d_in[2];
  const float* qkv_w  = (const float*)d_in[3];
  const float* qkv_b  = (const float*)d_in[4];
  const float* rpb    = (const float*)d_in[5];
  const float* proj_w = (const float*)d_in[6];
  const float* proj_b = (const float*)d_in[7];
  const float* n2g    = (const float*)d_in[8];
  const float* n2b    = (const float*)d_in[9];
  const float* fc1_w  = (const float*)d_in[10];
  const float* fc1_b  = (const float*)d_in[11];
  const float* fc2_w  = (const float*)d_in[12];
  const float* fc2_b  = (const float*)d_in[13];

  char* ws = (char*)d_ws;
  u16*   wq     = (u16*)(ws + 0);          // 576x192 bf16
  u16*   wp     = (u16*)(ws + 221184);     // 192x192
  u16*   wf1    = (u16*)(ws + 294912);     // 384x192
  u16*   wf2    = (u16*)(ws + 442368);     // 192x384
  float* biaspf = (float*)(ws + 589824);   // packed rel-bias f32, 3538944 B
  u16*   xnbuf  = (u16*)(ws + 4194304);    // xn bf16 (25MB), later attn-out o
  u16*   qkvbuf = (u16*)(ws + 29360128);   // qkv bf16 (75.5MB); later xn2 (first 25MB)
  u16*   ybuf   = (u16*)(ws + 54525952);   // gelu(fc1) bf16 (50MB), inside old qkv region
  u16*   x2     = (u16*)(ws + 104857600);  // post-proj residual bf16 (25MB)

  wconv_kernel<<<dim3(6, 18), 256, 0, stream>>>(qkv_w, wq, 192, 576);
  wconv_kernel<<<dim3(6, 6),  256, 0, stream>>>(proj_w, wp, 192, 192);
  wconv_kernel<<<dim3(6, 12), 256, 0, stream>>>(fc1_w, wf1, 192, 384);
  wconv_kernel<<<dim3(12, 6), 256, 0, stream>>>(fc2_w, wf2, 384, 192);
  bias_pack_kernel<<<216, 512, 0, stream>>>(rpb, biaspf);

  ln_kernel<float><<<16384, 256, 0, stream>>>(x, n1g, n1b, xnbuf);
  gemm_kernel<576, 192, 3><<<dim3(512, 9), 256, 0, stream>>>(xnbuf, wq, qkv_b, nullptr, qkvbuf);
  attn_kernel<<<1536, 512, 0, stream>>>(qkvbuf, biaspf, xnbuf);
  gemm_kernel<192, 192, 4><<<dim3(512, 3), 256, 0, stream>>>(xnbuf, wp, proj_b, x, x2);
  ln_kernel<u16><<<16384, 256, 0, stream>>>(x2, n2g, n2b, qkvbuf);
  gemm_kernel<384, 192, 2><<<dim3(512, 6), 256, 0, stream>>>(qkvbuf, wf1, fc1_b, nullptr, ybuf);
  gemm_kernel<192, 384, 5><<<dim3(512, 3), 256, 0, stream>>>(ybuf, wf2, fc2_b, x2, (float*)d_out);
}

// Round 5
// 313.888 us; speedup vs baseline: 1.6484x; 1.1290x over previous
//
#include <hip/hip_runtime.h>

using u16    = unsigned short;
using bf16x8 = __attribute__((ext_vector_type(8))) short;
using bf16x4 = __attribute__((ext_vector_type(4))) short;
using f32x4  = __attribute__((ext_vector_type(4))) float;
using i32x4  = __attribute__((ext_vector_type(4))) int;
using i32x2  = __attribute__((ext_vector_type(2))) int;

#define QSCALE 0.2550351115f   // (1/sqrt(32)) * log2(e)
#define LOG2E  1.4426950408889634f

__device__ __forceinline__ u16 f2b(float f) {
  unsigned u = __builtin_bit_cast(unsigned, f);
  u = (u + 0x7fffu + ((u >> 16) & 1u)) >> 16;
  return (u16)u;
}
__device__ __forceinline__ float b2f(u16 h) {
  return __builtin_bit_cast(float, ((unsigned)h) << 16);
}
__device__ __forceinline__ int cvt_pk(float a, float b) {
  int r;
  asm("v_cvt_pk_bf16_f32 %0, %1, %2" : "=v"(r) : "v"(a), "v"(b));
  return r;
}
__device__ __forceinline__ void gload_lds16(const u16* g, u16* l) {
  __builtin_amdgcn_global_load_lds(
      (const __attribute__((address_space(1))) unsigned int*)(g),
      (__attribute__((address_space(3))) unsigned int*)(l), 16, 0, 0);
}

// ---------------- weight transpose f32 -> bf16, LDS-tiled, coalesced both sides
__global__ __launch_bounds__(256) void wconv_kernel(const float* __restrict__ src,
                                                    u16* __restrict__ dst, int K, int N) {
  __shared__ u16 tile[32][33];
  int kb = blockIdx.x * 32, nb = blockIdx.y * 32;
  int tx = threadIdx.x & 31, ty = threadIdx.x >> 5;   // 32 x 8
#pragma unroll
  for (int r = 0; r < 32; r += 8)
    tile[ty + r][tx] = f2b(src[(size_t)(kb + ty + r) * N + nb + tx]);
  __syncthreads();
#pragma unroll
  for (int r = 0; r < 32; r += 8)
    dst[(size_t)(nb + ty + r) * K + kb + tx] = tile[tx][ty + r];
}

// ---------------- relative-bias pre-pack: f32 * log2e, C-fragment order ------
// 512-thread layout: biaspf[((h*36+kt)*512 + t)*8 + qc*4 + r]
//   q = (t>>6)*32 + qc*16 + (t&15), k = kt*16 + ((t>>4)&3)*4 + r
__global__ void bias_pack_kernel(const float* __restrict__ table, float* __restrict__ biaspf) {
  int bid = blockIdx.x;            // h*36 + kt
  int h = bid / 36, kt = bid - h * 36;
  int t = threadIdx.x;
  int w = t >> 6, lo = t & 15, lg = (t >> 4) & 3;
  float out[8];
#pragma unroll
  for (int qc = 0; qc < 2; ++qc)
#pragma unroll
    for (int r = 0; r < 4; ++r) {
      int q = w * 32 + qc * 16 + lo;
      int k = kt * 16 + lg * 4 + r;
      int i = q >> 4, j = q & 15;
      int oi = k / 24, oj = k - oi * 24;
      int idx = (i - oi + 23) * 39 + (j - oj + 23);
      out[qc * 4 + r] = table[idx * 6 + h] * LOG2E;
    }
  float* dst = biaspf + ((size_t)(bid * 512 + t)) * 8;
  *(f32x4*)dst       = *(const f32x4*)out;
  *(f32x4*)(dst + 4) = *(const f32x4*)(out + 4);
}

// ---------------- LayerNorm (192 cols) -> bf16, templated input type --------
template <typename TI>
__global__ __launch_bounds__(256) void ln_kernel(const TI* __restrict__ xin,
                                                 const float* __restrict__ g,
                                                 const float* __restrict__ b,
                                                 u16* __restrict__ out) {
  int row = blockIdx.x * 4 + (threadIdx.x >> 6);
  int l = threadIdx.x & 63;
  const TI* xr = xin + (size_t)row * 192;
  float v0, v1, v2;
  if constexpr (sizeof(TI) == 2) {
    v0 = b2f(xr[l]); v1 = b2f(xr[l + 64]); v2 = b2f(xr[l + 128]);
  } else {
    v0 = xr[l]; v1 = xr[l + 64]; v2 = xr[l + 128];
  }
  float s1 = v0 + v1 + v2;
  float s2 = v0 * v0 + v1 * v1 + v2 * v2;
#pragma unroll
  for (int off = 32; off; off >>= 1) {
    s1 += __shfl_xor(s1, off);
    s2 += __shfl_xor(s2, off);
  }
  float mu = s1 * (1.0f / 192.0f);
  float var = s2 * (1.0f / 192.0f) - mu * mu;
  float rs = rsqrtf(var + 1e-5f);
  u16* orow = out + (size_t)row * 192;
  orow[l]       = f2b((v0 - mu) * rs * g[l]       + b[l]);
  orow[l + 64]  = f2b((v1 - mu) * rs * g[l + 64]  + b[l + 64]);
  orow[l + 128] = f2b((v2 - mu) * rs * g[l + 128] + b[l + 128]);
}

// ---------------- generic bf16 GEMM: C[M][N] = A[M][K] * WT[N][K]^T ---------
// BM=128, BN=64, 4 waves (2x2), wave tile 64x32, mfma 16x16x32 bf16.
// 1-D grid, N-fast work order + XCD-chunk swizzle: each XCD owns a contiguous
// (m-tiles x all n-tiles) range so A-panels are fetched from HBM once and
// served from that XCD's L2 across n-tiles.
// Staging via global_load_lds (16B), XOR-swizzled within 8-chunk groups.
// EPI 2: bf16 gelu(acc+bias); EPI 3: bf16 (acc+bias)*(n<192?QSCALE:1);
// EPI 4: bf16 acc+bias+res_f32; EPI 5: f32 acc+bias+res_bf16.
template <int N, int K, int EPI>
__global__ __launch_bounds__(256, 2) void gemm_kernel(
    const u16* __restrict__ A, const u16* __restrict__ WT,
    const float* __restrict__ bias, const void* __restrict__ res,
    void* __restrict__ outp) {
  __shared__ u16 As[128 * 192];
  __shared__ u16 Ws[64 * 192];
  const int t = threadIdx.x;
  const int l = t & 63, w = t >> 6;
  const int lo = l & 15, lg = l >> 4;
  constexpr int nbn = N / 64;
  const int bid = blockIdx.x;
  const int cpx = gridDim.x >> 3;
  const int wk = (bid & 7) * cpx + (bid >> 3);   // XCD-chunked, bijective (grid%8==0)
  const int bm0 = (wk / nbn) * 128, bn0 = (wk % nbn) * 64;
  const int wr = (w >> 1) * 64, wc = (w & 1) * 32;
  f32x4 acc[4][2] = {};
  for (int c0 = 0; c0 < K; c0 += 192) {
    if (c0) __syncthreads();
    // A: 3072 16B-units, unit u at LDS As[u*8]; global chunk xor-swizzled
#pragma unroll
    for (int i = 0; i < 12; ++i) {
      int u = t + i * 256;
      int row = u / 24, ch = u - row * 24;
      int cg = (ch & ~7) | ((ch ^ row) & 7);
      gload_lds16(&A[(size_t)(bm0 + row) * K + c0 + cg * 8], &As[u * 8]);
    }
#pragma unroll
    for (int i = 0; i < 6; ++i) {
      int u = t + i * 256;
      int row = u / 24, ch = u - row * 24;
      int cg = (ch & ~7) | ((ch ^ row) & 7);
      gload_lds16(&WT[(size_t)(bn0 + row) * K + c0 + cg * 8], &Ws[u * 8]);
    }
    __syncthreads();
#pragma unroll
    for (int kk = 0; kk < 6; ++kk) {
      int cb = kk * 4 + lg;
      int cofs = ((cb & ~7) | ((cb ^ lo) & 7)) * 8;   // rows of all frags == lo (mod 8)
      bf16x8 b0 = *(const bf16x8*)&Ws[(wc + lo) * 192 + cofs];
      bf16x8 b1 = *(const bf16x8*)&Ws[(wc + 16 + lo) * 192 + cofs];
#pragma unroll
      for (int mi = 0; mi < 4; ++mi) {
        bf16x8 a = *(const bf16x8*)&As[(wr + mi * 16 + lo) * 192 + cofs];
        acc[mi][0] = __builtin_amdgcn_mfma_f32_16x16x32_bf16(a, b0, acc[mi][0], 0, 0, 0);
        acc[mi][1] = __builtin_amdgcn_mfma_f32_16x16x32_bf16(a, b1, acc[mi][1], 0, 0, 0);
      }
    }
  }
#pragma unroll
  for (int ni = 0; ni < 2; ++ni) {
    int n = bn0 + wc + ni * 16 + lo;
    float bs = bias[n];
#pragma unroll
    for (int mi = 0; mi < 4; ++mi)
#pragma unroll
      for (int r = 0; r < 4; ++r) {
        int m = bm0 + wr + mi * 16 + lg * 4 + r;
        float v = acc[mi][ni][r] + bs;
        size_t idx = (size_t)m * N + n;
        if constexpr (EPI == 2) {
          float gg = 0.5f * v * (1.0f + erff(v * 0.70710678118654752f));
          ((u16*)outp)[idx] = f2b(gg);
        } else if constexpr (EPI == 3) {
          float sc = (n < 192) ? QSCALE : 1.0f;
          ((u16*)outp)[idx] = f2b(v * sc);
        } else if constexpr (EPI == 4) {
          ((u16*)outp)[idx] = f2b(v + ((const float*)res)[idx]);
        } else {
          ((float*)outp)[idx] = v + b2f(((const u16*)res)[idx]);
        }
      }
  }
}

// ---------------- attention: one 512-thread block per (window, head) --------
// 8 waves x 32 q-rows. Q pre-scaled by QSCALE; bias (f32, *log2e) is the QK^T
// MFMA C-operand, register-double-buffered one kt-pair ahead. p = exp2(c),
// packed via v_cvt_pk_bf16_f32; PV as 16x16x32 over kt-pairs with
// sigma-permuted + row-XOR-swizzled V slots (conflict-free staging).
// XCD-chunked block swizzle keeps spatially-adjacent windows (overlapping K/V
// stripes, shared 128B lines across heads) in one XCD's L2.
__global__ __launch_bounds__(512, 4) void attn_kernel(const u16* __restrict__ qkv,
                                                      const float* __restrict__ biaspf,
                                                      u16* __restrict__ o_out) {
  __shared__ u16 Kl[576 * 36];
  __shared__ u16 VT[32 * 600];
  const int bid = blockIdx.x;
  const int wk = (bid & 7) * 192 + (bid >> 3);   // 1536 blocks, bijective
  const int h = wk % 6;
  const int wid = wk / 6;
  const int bb = wid >> 6, wy = (wid >> 3) & 7, wx = wid & 7;
  const int t = threadIdx.x;
  const int w = t >> 6, lo = t & 15, lg = (t >> 4) & 3;

  // stage K (row-major, stride 36) and V (transposed, sigma slot permute +
  // row-XOR bank swizzle)
#pragma unroll
  for (int i2 = 0; i2 < 5; ++i2) {
    int u = t + i2 * 512;                 // 2304 units = 576 pos x 4 quarters
    if (u < 2304) {
      int pos = u >> 2, d0 = (u & 3) * 8;
      int oi = pos / 24, oj = pos - oi * 24;
      int y = wy * 16 - 4 + oi, x = wx * 16 - 4 + oj;
      i32x4 kv = {0, 0, 0, 0};
      bf16x8 vv = {0, 0, 0, 0, 0, 0, 0, 0};
      if ((unsigned)y < 128u && (unsigned)x < 128u) {
        const u16* s = qkv + (size_t)((bb << 14) + y * 128 + x) * 576 + h * 32 + d0;
        kv = *(const i32x4*)(s + 192);
        vv = *(const bf16x8*)(s + 384);
      }
      i32x2 klo = {kv[0], kv[1]}, khi = {kv[2], kv[3]};
      *(i32x2*)&Kl[pos * 36 + d0]     = klo;
      *(i32x2*)&Kl[pos * 36 + d0 + 4] = khi;
      // sigma: slot = ((pos>>2)&3)*8 + ((pos>>4)&1)*4 + (pos&3) within 32-block
      int p5 = pos & 31;
      int slot = (((p5 >> 2) & 3) << 3) | (((p5 >> 4) & 1) << 2) | (p5 & 3);
      int base = (pos & ~31);
#pragma unroll
      for (int j = 0; j < 8; ++j) {
        int row = d0 + j;
        int scol = (slot & 7) | ((((slot >> 3) ^ (row >> 3)) & 3) << 3);
        VT[row * 600 + base + scol] = (u16)vv[j];
      }
    }
  }

  // Q fragments: B-operand layout (col = q = lo, k-dims = lg*8..+7)
  bf16x8 qf[2];
#pragma unroll
  for (int qc = 0; qc < 2; ++qc) {
    int yy = wy * 16 + w * 2 + qc, xx = wx * 16 + lo;
    qf[qc] = *(const bf16x8*)(qkv + (size_t)((bb << 14) + yy * 128 + xx) * 576 + h * 32 + lg * 8);
  }
  __syncthreads();

  float ls[2] = {0.0f, 0.0f};
  f32x4 oacc[2][2] = {};
  const f32x4* bbase = (const f32x4*)(biaspf + ((size_t)(h * 36) * 512 + t) * 8);
  // bbase stride per kt = 512*8 floats = 1024 f32x4
  f32x4 bc[4];   // current pair bias: [hf*2+qc]
#pragma unroll
  for (int i = 0; i < 4; ++i) bc[i] = bbase[(i >> 1) * 1024 + (i & 1)];
  const int xr0 = lo >> 3, xr1 = 2 | (lo >> 3);

  for (int kt2 = 0; kt2 < 18; ++kt2) {
    // prefetch next kt-pair's bias (clamped on last iteration)
    int ktn = (kt2 < 17) ? (kt2 + 1) : 17;
    f32x4 bn[4];
#pragma unroll
    for (int i = 0; i < 4; ++i) bn[i] = bbase[(2 * ktn + (i >> 1)) * 1024 + (i & 1)];

    i32x4 pw[2];
#pragma unroll
    for (int hf = 0; hf < 2; ++hf) {
      int kt = kt2 * 2 + hf;
      int krow = (kt * 16 + lo) * 36 + lg * 8;
      bf16x4 k0 = *(const bf16x4*)&Kl[krow];
      bf16x4 k1 = *(const bf16x4*)&Kl[krow + 4];
      bf16x8 kf = {k0[0], k0[1], k0[2], k0[3], k1[0], k1[1], k1[2], k1[3]};
#pragma unroll
      for (int qc = 0; qc < 2; ++qc) {
        f32x4 c = __builtin_amdgcn_mfma_f32_16x16x32_bf16(kf, qf[qc], bc[hf * 2 + qc], 0, 0, 0);
        float p0 = __builtin_amdgcn_exp2f(c[0]);
        float p1 = __builtin_amdgcn_exp2f(c[1]);
        float p2 = __builtin_amdgcn_exp2f(c[2]);
        float p3 = __builtin_amdgcn_exp2f(c[3]);
        ls[qc] += (p0 + p1) + (p2 + p3);
        pw[qc][hf * 2 + 0] = cvt_pk(p0, p1);
        pw[qc][hf * 2 + 1] = cvt_pk(p2, p3);
      }
    }
    int vb = kt2 * 32;
    bf16x8 vb0 = *(const bf16x8*)&VT[lo * 600 + vb + ((lg ^ xr0) & 3) * 8];
    bf16x8 vb1 = *(const bf16x8*)&VT[(16 + lo) * 600 + vb + ((lg ^ xr1) & 3) * 8];
#pragma unroll
    for (int qc = 0; qc < 2; ++qc) {
      bf16x8 pa = __builtin_bit_cast(bf16x8, pw[qc]);
      oacc[qc][0] = __builtin_amdgcn_mfma_f32_16x16x32_bf16(pa, vb0, oacc[qc][0], 0, 0, 0);
      oacc[qc][1] = __builtin_amdgcn_mfma_f32_16x16x32_bf16(pa, vb1, oacc[qc][1], 0, 0, 0);
    }
#pragma unroll
    for (int i = 0; i < 4; ++i) bc[i] = bn[i];
  }

  // normalize + store
#pragma unroll
  for (int qc = 0; qc < 2; ++qc) {
    float s = ls[qc];
    s += __shfl_xor(s, 16);
    s += __shfl_xor(s, 32);
    float linv = 1.0f / s;
#pragma unroll
    for (int r = 0; r < 4; ++r) {
      float lv = __shfl(linv, lg * 4 + r);
      int yy = wy * 16 + w * 2 + qc, xx = wx * 16 + lg * 4 + r;
      u16* dst = o_out + (size_t)((bb << 14) + yy * 128 + xx) * 192 + h * 32 + lo;
      dst[0]  = f2b(oacc[qc][0][r] * lv);
      dst[16] = f2b(oacc[qc][1][r] * lv);
    }
  }
}

// ---------------- launcher ---------------------------------------------------
extern "C" void kernel_launch(void* const* d_in, const int* in_sizes, int n_in,
                              void* d_out, int out_size, void* d_ws, size_t ws_size,
                              hipStream_t stream) {
  (void)in_sizes; (void)n_in; (void)out_size; (void)ws_size;
  const float* x      = (const float*)d_in[0];
  const float* n1g    = (const float*)d_in[1];
  const float* n1b    = (const float*)d_in[2];
  const float* qkv_w  = (const float*)d_in[3];
  const float* qkv_b  = (const float*)d_in[4];
  const float* rpb    = (const float*)d_in[5];
  const float* proj_w = (const float*)d_in[6];
  const float* proj_b = (const float*)d_in[7];
  const float* n2g    = (const float*)d_in[8];
  const float* n2b    = (const float*)d_in[9];
  const float* fc1_w  = (const float*)d_in[10];
  const float* fc1_b  = (const float*)d_in[11];
  const float* fc2_w  = (const float*)d_in[12];
  const float* fc2_b  = (const float*)d_in[13];

  char* ws = (char*)d_ws;
  u16*   wq     = (u16*)(ws + 0);          // 576x192 bf16
  u16*   wp     = (u16*)(ws + 221184);     // 192x192
  u16*   wf1    = (u16*)(ws + 294912);     // 384x192
  u16*   wf2    = (u16*)(ws + 442368);     // 192x384
  float* biaspf = (float*)(ws + 589824);   // packed rel-bias f32, 3538944 B
  u16*   xnbuf  = (u16*)(ws + 4194304);    // xn bf16 (25MB), later attn-out o
  u16*   qkvbuf = (u16*)(ws + 29360128);   // qkv bf16 (75.5MB); later xn2 (first 25MB)
  u16*   ybuf   = (u16*)(ws + 54525952);   // gelu(fc1) bf16 (50MB), inside old qkv region
  u16*   x2     = (u16*)(ws + 104857600);  // post-proj residual bf16 (25MB)

  wconv_kernel<<<dim3(6, 18), 256, 0, stream>>>(qkv_w, wq, 192, 576);
  wconv_kernel<<<dim3(6, 6),  256, 0, stream>>>(proj_w, wp, 192, 192);
  wconv_kernel<<<dim3(6, 12), 256, 0, stream>>>(fc1_w, wf1, 192, 384);
  wconv_kernel<<<dim3(12, 6), 256, 0, stream>>>(fc2_w, wf2, 384, 192);
  bias_pack_kernel<<<216, 512, 0, stream>>>(rpb, biaspf);

  ln_kernel<float><<<16384, 256, 0, stream>>>(x, n1g, n1b, xnbuf);
  gemm_kernel<576, 192, 3><<<4608, 256, 0, stream>>>(xnbuf, wq, qkv_b, nullptr, qkvbuf);
  attn_kernel<<<1536, 512, 0, stream>>>(qkvbuf, biaspf, xnbuf);
  gemm_kernel<192, 192, 4><<<1536, 256, 0, stream>>>(xnbuf, wp, proj_b, x, x2);
  ln_kernel<u16><<<16384, 256, 0, stream>>>(x2, n2g, n2b, qkvbuf);
  gemm_kernel<384, 192, 2><<<3072, 256, 0, stream>>>(qkvbuf, wf1, fc1_b, nullptr, ybuf);
  gemm_kernel<192, 384, 5><<<1536, 256, 0, stream>>>(ybuf, wf2, fc2_b, x2, (float*)d_out);
}

// Round 6
// 299.888 us; speedup vs baseline: 1.7254x; 1.0467x over previous
//
#include <hip/hip_runtime.h>

using u16    = unsigned short;
using bf16x8 = __attribute__((ext_vector_type(8))) short;
using bf16x4 = __attribute__((ext_vector_type(4))) short;
using f32x4  = __attribute__((ext_vector_type(4))) float;
using i32x4  = __attribute__((ext_vector_type(4))) int;
using i32x2  = __attribute__((ext_vector_type(2))) int;

#define QSCALE 0.2550351115f   // (1/sqrt(32)) * log2(e)
#define LOG2E  1.4426950408889634f

__device__ __forceinline__ u16 f2b(float f) {
  unsigned u = __builtin_bit_cast(unsigned, f);
  u = (u + 0x7fffu + ((u >> 16) & 1u)) >> 16;
  return (u16)u;
}
__device__ __forceinline__ float b2f(u16 h) {
  return __builtin_bit_cast(float, ((unsigned)h) << 16);
}
__device__ __forceinline__ int cvt_pk(float a, float b) {
  int r;
  asm("v_cvt_pk_bf16_f32 %0, %1, %2" : "=v"(r) : "v"(a), "v"(b));
  return r;
}
__device__ __forceinline__ void gload_lds16(const u16* g, u16* l) {
  __builtin_amdgcn_global_load_lds(
      (const __attribute__((address_space(1))) unsigned int*)(g),
      (__attribute__((address_space(3))) unsigned int*)(l), 16, 0, 0);
}

// ---------------- weight transpose f32 -> bf16, LDS-tiled, coalesced both sides
__global__ __launch_bounds__(256) void wconv_kernel(const float* __restrict__ src,
                                                    u16* __restrict__ dst, int K, int N) {
  __shared__ u16 tile[32][33];
  int kb = blockIdx.x * 32, nb = blockIdx.y * 32;
  int tx = threadIdx.x & 31, ty = threadIdx.x >> 5;   // 32 x 8
#pragma unroll
  for (int r = 0; r < 32; r += 8)
    tile[ty + r][tx] = f2b(src[(size_t)(kb + ty + r) * N + nb + tx]);
  __syncthreads();
#pragma unroll
  for (int r = 0; r < 32; r += 8)
    dst[(size_t)(nb + ty + r) * K + kb + tx] = tile[tx][ty + r];
}

// ---------------- relative-bias pre-pack: f32 * log2e, C-fragment order ------
// 512-thread layout: biaspf[((h*36+kt)*512 + t)*8 + qc*4 + r]
//   q = (t>>6)*32 + qc*16 + (t&15), k = kt*16 + ((t>>4)&3)*4 + r
__global__ void bias_pack_kernel(const float* __restrict__ table, float* __restrict__ biaspf) {
  int bid = blockIdx.x;            // h*36 + kt
  int h = bid / 36, kt = bid - h * 36;
  int t = threadIdx.x;
  int w = t >> 6, lo = t & 15, lg = (t >> 4) & 3;
  float out[8];
#pragma unroll
  for (int qc = 0; qc < 2; ++qc)
#pragma unroll
    for (int r = 0; r < 4; ++r) {
      int q = w * 32 + qc * 16 + lo;
      int k = kt * 16 + lg * 4 + r;
      int i = q >> 4, j = q & 15;
      int oi = k / 24, oj = k - oi * 24;
      int idx = (i - oi + 23) * 39 + (j - oj + 23);
      out[qc * 4 + r] = table[idx * 6 + h] * LOG2E;
    }
  float* dst = biaspf + ((size_t)(bid * 512 + t)) * 8;
  *(f32x4*)dst       = *(const f32x4*)out;
  *(f32x4*)(dst + 4) = *(const f32x4*)(out + 4);
}

// ---------------- A-stationary GEMM, optional fused input-LN -----------------
// Block owns a 128-row A panel (staged once), loops N/64 n-tiles with
// single-buffered W staging (next stage issued before the epilogue so load
// latency hides under stores). 4 waves (2x2), wave tile 64x32, mfma 16x16x32.
// LNIN: A is f32, LayerNorm'ed in-register into a pad-200 LDS tile.
// EPI 2: bf16 gelu(acc+bias); EPI 3: bf16 (acc+bias)*(nt<3?QSCALE:1).
template <int N, int EPI, bool LNIN>
__global__ __launch_bounds__(256, 2) void gemm_as_kernel(
    const void* __restrict__ Ap, const u16* __restrict__ WT,
    const float* __restrict__ bias, const float* __restrict__ lng,
    const float* __restrict__ lnb, u16* __restrict__ outp) {
  constexpr int AST = LNIN ? 200 : 192;
  __shared__ u16 As[128 * AST];
  __shared__ u16 Ws[64 * 192];
  const int t = threadIdx.x;
  const int l = t & 63, w = t >> 6;
  const int lo = l & 15, lg = l >> 4;
  const int m0 = blockIdx.x * 128;
  const int wr = (w >> 1) * 64, wc = (w & 1) * 32;

  if constexpr (LNIN) {
    const float* A = (const float*)Ap;
    float ga = lng[l], gb = lng[l + 64], gc = lng[l + 128];
    float ba = lnb[l], bb = lnb[l + 64], bc = lnb[l + 128];
    for (int rb = 0; rb < 32; rb += 8) {
      float vv[8][3];
#pragma unroll
      for (int rr = 0; rr < 8; ++rr) {
        int row = w * 32 + rb + rr;
        const float* xr = A + (size_t)(m0 + row) * 192;
        vv[rr][0] = xr[l]; vv[rr][1] = xr[l + 64]; vv[rr][2] = xr[l + 128];
      }
#pragma unroll
      for (int rr = 0; rr < 8; ++rr) {
        int row = w * 32 + rb + rr;
        float s1 = vv[rr][0] + vv[rr][1] + vv[rr][2];
        float s2 = vv[rr][0] * vv[rr][0] + vv[rr][1] * vv[rr][1] + vv[rr][2] * vv[rr][2];
#pragma unroll
        for (int off = 32; off; off >>= 1) {
          s1 += __shfl_xor(s1, off);
          s2 += __shfl_xor(s2, off);
        }
        float mu = s1 * (1.0f / 192.0f);
        float var = s2 * (1.0f / 192.0f) - mu * mu;
        float rs = rsqrtf(var + 1e-5f);
        u16* ar = &As[row * 200];
        ar[l]       = f2b((vv[rr][0] - mu) * rs * ga + ba);
        ar[l + 64]  = f2b((vv[rr][1] - mu) * rs * gb + bb);
        ar[l + 128] = f2b((vv[rr][2] - mu) * rs * gc + bc);
      }
    }
  } else {
    const u16* A = (const u16*)Ap;
#pragma unroll
    for (int i = 0; i < 12; ++i) {
      int u = t + i * 256;
      int row = u / 24, ch = u - row * 24;
      int cg = (ch & ~7) | ((ch ^ row) & 7);
      gload_lds16(&A[(size_t)(m0 + row) * 192 + cg * 8], &As[u * 8]);
    }
  }

  auto stageW = [&](int nt) {
#pragma unroll
    for (int i = 0; i < 6; ++i) {
      int u = t + i * 256;
      int row = u / 24, ch = u - row * 24;
      int cg = (ch & ~7) | ((ch ^ row) & 7);
      gload_lds16(&WT[(size_t)(nt * 64 + row) * 192 + cg * 8], &Ws[u * 8]);
    }
  };
  stageW(0);
  constexpr int NT = N / 64;
  for (int nt = 0; nt < NT; ++nt) {
    __syncthreads();
    f32x4 acc[4][2] = {};
#pragma unroll
    for (int kk = 0; kk < 6; ++kk) {
      int cb = kk * 4 + lg;
      int cofs = ((cb & ~7) | ((cb ^ lo) & 7)) * 8;
      bf16x8 wb0 = *(const bf16x8*)&Ws[(wc + lo) * 192 + cofs];
      bf16x8 wb1 = *(const bf16x8*)&Ws[(wc + 16 + lo) * 192 + cofs];
#pragma unroll
      for (int mi = 0; mi < 4; ++mi) {
        bf16x8 a;
        if constexpr (LNIN) a = *(const bf16x8*)&As[(wr + mi * 16 + lo) * 200 + kk * 32 + lg * 8];
        else                a = *(const bf16x8*)&As[(wr + mi * 16 + lo) * 192 + cofs];
        acc[mi][0] = __builtin_amdgcn_mfma_f32_16x16x32_bf16(a, wb0, acc[mi][0], 0, 0, 0);
        acc[mi][1] = __builtin_amdgcn_mfma_f32_16x16x32_bf16(a, wb1, acc[mi][1], 0, 0, 0);
      }
    }
    __syncthreads();
    if (nt + 1 < NT) stageW(nt + 1);
#pragma unroll
    for (int ni = 0; ni < 2; ++ni) {
      int n = nt * 64 + wc + ni * 16 + lo;
      float bs = bias[n];
#pragma unroll
      for (int mi = 0; mi < 4; ++mi)
#pragma unroll
        for (int r = 0; r < 4; ++r) {
          int m = m0 + wr + mi * 16 + lg * 4 + r;
          float v = acc[mi][ni][r] + bs;
          if constexpr (EPI == 2)
            v = 0.5f * v * (1.0f + erff(v * 0.70710678118654752f));
          if constexpr (EPI == 3)
            v *= (nt < 3) ? QSCALE : 1.0f;
          outp[(size_t)m * N + n] = f2b(v);
        }
    }
  }
}

// ---------------- proj GEMM + residual + fused LN2 ---------------------------
// BM=128, BN=192 (full rows via 3 passes, acc kept). v = acc+proj_b+x (f32),
// row stats via 16-lane shuffle + cross-wave LDS reduce; writes x2 (bf16) and
// xn2 = LN(v) (bf16).
__global__ __launch_bounds__(256, 2) void proj_ln_kernel(
    const u16* __restrict__ o, const u16* __restrict__ WT,
    const float* __restrict__ bias, const float* __restrict__ xres,
    const float* __restrict__ g2, const float* __restrict__ b2,
    u16* __restrict__ x2, u16* __restrict__ xn2) {
  __shared__ u16 As[128 * 192];
  __shared__ u16 Ws[64 * 192];
  __shared__ float red[128][4];
  const int t = threadIdx.x;
  const int l = t & 63, w = t >> 6;
  const int lo = l & 15, lg = l >> 4;
  const int m0 = blockIdx.x * 128;
  const int wr = (w >> 1) * 64, wc = (w & 1) * 32;

#pragma unroll
  for (int i = 0; i < 12; ++i) {
    int u = t + i * 256;
    int row = u / 24, ch = u - row * 24;
    int cg = (ch & ~7) | ((ch ^ row) & 7);
    gload_lds16(&o[(size_t)(m0 + row) * 192 + cg * 8], &As[u * 8]);
  }
  auto stageW = [&](int p) {
#pragma unroll
    for (int i = 0; i < 6; ++i) {
      int u = t + i * 256;
      int row = u / 24, ch = u - row * 24;
      int cg = (ch & ~7) | ((ch ^ row) & 7);
      gload_lds16(&WT[(size_t)(p * 64 + row) * 192 + cg * 8], &Ws[u * 8]);
    }
  };
  stageW(0);
  f32x4 acc[3][4][2] = {};
#pragma unroll
  for (int p = 0; p < 3; ++p) {
    __syncthreads();
#pragma unroll
    for (int kk = 0; kk < 6; ++kk) {
      int cb = kk * 4 + lg;
      int cofs = ((cb & ~7) | ((cb ^ lo) & 7)) * 8;
      bf16x8 wb0 = *(const bf16x8*)&Ws[(wc + lo) * 192 + cofs];
      bf16x8 wb1 = *(const bf16x8*)&Ws[(wc + 16 + lo) * 192 + cofs];
#pragma unroll
      for (int mi = 0; mi < 4; ++mi) {
        bf16x8 a = *(const bf16x8*)&As[(wr + mi * 16 + lo) * 192 + cofs];
        acc[p][mi][0] = __builtin_amdgcn_mfma_f32_16x16x32_bf16(a, wb0, acc[p][mi][0], 0, 0, 0);
        acc[p][mi][1] = __builtin_amdgcn_mfma_f32_16x16x32_bf16(a, wb1, acc[p][mi][1], 0, 0, 0);
      }
    }
    __syncthreads();
    if (p < 2) stageW(p + 1);
  }

  // v = acc + bias + res (f32), accumulate row stats
  float bcol[3][2];
#pragma unroll
  for (int p = 0; p < 3; ++p)
#pragma unroll
    for (int ni = 0; ni < 2; ++ni) bcol[p][ni] = bias[p * 64 + wc + ni * 16 + lo];
  float s1[4][4] = {}, s2[4][4] = {};
#pragma unroll
  for (int p = 0; p < 3; ++p)
#pragma unroll
    for (int ni = 0; ni < 2; ++ni) {
      int col = p * 64 + wc + ni * 16 + lo;
#pragma unroll
      for (int mi = 0; mi < 4; ++mi)
#pragma unroll
        for (int r = 0; r < 4; ++r) {
          int m = m0 + wr + mi * 16 + lg * 4 + r;
          float v = acc[p][mi][ni][r] + bcol[p][ni] + xres[(size_t)m * 192 + col];
          acc[p][mi][ni][r] = v;
          s1[mi][r] += v;
          s2[mi][r] += v * v;
        }
    }
#pragma unroll
  for (int mi = 0; mi < 4; ++mi)
#pragma unroll
    for (int r = 0; r < 4; ++r) {
#pragma unroll
      for (int off = 8; off; off >>= 1) {
        s1[mi][r] += __shfl_xor(s1[mi][r], off);
        s2[mi][r] += __shfl_xor(s2[mi][r], off);
      }
      if (lo == 0) {
        int row = wr + mi * 16 + lg * 4 + r;
        red[row][wc == 0 ? 0 : 2] = s1[mi][r];
        red[row][wc == 0 ? 1 : 3] = s2[mi][r];
      }
    }
  __syncthreads();

  float gcol[3][2], b2col[3][2];
#pragma unroll
  for (int p = 0; p < 3; ++p)
#pragma unroll
    for (int ni = 0; ni < 2; ++ni) {
      int col = p * 64 + wc + ni * 16 + lo;
      gcol[p][ni] = g2[col];
      b2col[p][ni] = b2[col];
    }
#pragma unroll
  for (int mi = 0; mi < 4; ++mi)
#pragma unroll
    for (int r = 0; r < 4; ++r) {
      int row = wr + mi * 16 + lg * 4 + r;
      int m = m0 + row;
      float S1 = red[row][0] + red[row][2];
      float S2 = red[row][1] + red[row][3];
      float mu = S1 * (1.0f / 192.0f);
      float var = S2 * (1.0f / 192.0f) - mu * mu;
      float rs = rsqrtf(var + 1e-5f);
#pragma unroll
      for (int p = 0; p < 3; ++p)
#pragma unroll
        for (int ni = 0; ni < 2; ++ni) {
          int col = p * 64 + wc + ni * 16 + lo;
          float v = acc[p][mi][ni][r];
          x2[(size_t)m * 192 + col]  = f2b(v);
          xn2[(size_t)m * 192 + col] = f2b((v - mu) * rs * gcol[p][ni] + b2col[p][ni]);
        }
    }
}

// ---------------- fc2 GEMM (K=384 loop): C = A*WT^T + bias + res -------------
template <int N, int K, int EPI>
__global__ __launch_bounds__(256, 2) void gemm_kernel(
    const u16* __restrict__ A, const u16* __restrict__ WT,
    const float* __restrict__ bias, const void* __restrict__ res,
    void* __restrict__ outp) {
  __shared__ u16 As[128 * 192];
  __shared__ u16 Ws[64 * 192];
  const int t = threadIdx.x;
  const int l = t & 63, w = t >> 6;
  const int lo = l & 15, lg = l >> 4;
  constexpr int nbn = N / 64;
  const int bid = blockIdx.x;
  const int cpx = gridDim.x >> 3;
  const int wk = (bid & 7) * cpx + (bid >> 3);   // XCD-chunked, bijective (grid%8==0)
  const int bm0 = (wk / nbn) * 128, bn0 = (wk % nbn) * 64;
  const int wr = (w >> 1) * 64, wc = (w & 1) * 32;
  f32x4 acc[4][2] = {};
  for (int c0 = 0; c0 < K; c0 += 192) {
    if (c0) __syncthreads();
#pragma unroll
    for (int i = 0; i < 12; ++i) {
      int u = t + i * 256;
      int row = u / 24, ch = u - row * 24;
      int cg = (ch & ~7) | ((ch ^ row) & 7);
      gload_lds16(&A[(size_t)(bm0 + row) * K + c0 + cg * 8], &As[u * 8]);
    }
#pragma unroll
    for (int i = 0; i < 6; ++i) {
      int u = t + i * 256;
      int row = u / 24, ch = u - row * 24;
      int cg = (ch & ~7) | ((ch ^ row) & 7);
      gload_lds16(&WT[(size_t)(bn0 + row) * K + c0 + cg * 8], &Ws[u * 8]);
    }
    __syncthreads();
#pragma unroll
    for (int kk = 0; kk < 6; ++kk) {
      int cb = kk * 4 + lg;
      int cofs = ((cb & ~7) | ((cb ^ lo) & 7)) * 8;
      bf16x8 b0 = *(const bf16x8*)&Ws[(wc + lo) * 192 + cofs];
      bf16x8 b1 = *(const bf16x8*)&Ws[(wc + 16 + lo) * 192 + cofs];
#pragma unroll
      for (int mi = 0; mi < 4; ++mi) {
        bf16x8 a = *(const bf16x8*)&As[(wr + mi * 16 + lo) * 192 + cofs];
        acc[mi][0] = __builtin_amdgcn_mfma_f32_16x16x32_bf16(a, b0, acc[mi][0], 0, 0, 0);
        acc[mi][1] = __builtin_amdgcn_mfma_f32_16x16x32_bf16(a, b1, acc[mi][1], 0, 0, 0);
      }
    }
  }
#pragma unroll
  for (int ni = 0; ni < 2; ++ni) {
    int n = bn0 + wc + ni * 16 + lo;
    float bs = bias[n];
#pragma unroll
    for (int mi = 0; mi < 4; ++mi)
#pragma unroll
      for (int r = 0; r < 4; ++r) {
        int m = bm0 + wr + mi * 16 + lg * 4 + r;
        float v = acc[mi][ni][r] + bs;
        size_t idx = (size_t)m * N + n;
        if constexpr (EPI == 5) {
          ((float*)outp)[idx] = v + b2f(((const u16*)res)[idx]);
        } else {
          ((u16*)outp)[idx] = f2b(v);
        }
      }
  }
}

// ---------------- attention: one 512-thread block per (window, head) --------
__global__ __launch_bounds__(512, 4) void attn_kernel(const u16* __restrict__ qkv,
                                                      const float* __restrict__ biaspf,
                                                      u16* __restrict__ o_out) {
  __shared__ u16 Kl[576 * 36];
  __shared__ u16 VT[32 * 600];
  const int bid = blockIdx.x;
  const int wk = (bid & 7) * 192 + (bid >> 3);   // 1536 blocks, bijective
  const int h = wk % 6;
  const int wid = wk / 6;
  const int bb = wid >> 6, wy = (wid >> 3) & 7, wx = wid & 7;
  const int t = threadIdx.x;
  const int w = t >> 6, lo = t & 15, lg = (t >> 4) & 3;

#pragma unroll
  for (int i2 = 0; i2 < 5; ++i2) {
    int u = t + i2 * 512;                 // 2304 units = 576 pos x 4 quarters
    if (u < 2304) {
      int pos = u >> 2, d0 = (u & 3) * 8;
      int oi = pos / 24, oj = pos - oi * 24;
      int y = wy * 16 - 4 + oi, x = wx * 16 - 4 + oj;
      i32x4 kv = {0, 0, 0, 0};
      bf16x8 vv = {0, 0, 0, 0, 0, 0, 0, 0};
      if ((unsigned)y < 128u && (unsigned)x < 128u) {
        const u16* s = qkv + (size_t)((bb << 14) + y * 128 + x) * 576 + h * 32 + d0;
        kv = *(const i32x4*)(s + 192);
        vv = *(const bf16x8*)(s + 384);
      }
      i32x2 klo = {kv[0], kv[1]}, khi = {kv[2], kv[3]};
      *(i32x2*)&Kl[pos * 36 + d0]     = klo;
      *(i32x2*)&Kl[pos * 36 + d0 + 4] = khi;
      int p5 = pos & 31;
      int slot = (((p5 >> 2) & 3) << 3) | (((p5 >> 4) & 1) << 2) | (p5 & 3);
      int base = (pos & ~31);
#pragma unroll
      for (int j = 0; j < 8; ++j) {
        int row = d0 + j;
        int scol = (slot & 7) | ((((slot >> 3) ^ (row >> 3)) & 3) << 3);
        VT[row * 600 + base + scol] = (u16)vv[j];
      }
    }
  }

  bf16x8 qf[2];
#pragma unroll
  for (int qc = 0; qc < 2; ++qc) {
    int yy = wy * 16 + w * 2 + qc, xx = wx * 16 + lo;
    qf[qc] = *(const bf16x8*)(qkv + (size_t)((bb << 14) + yy * 128 + xx) * 576 + h * 32 + lg * 8);
  }
  __syncthreads();

  float ls[2] = {0.0f, 0.0f};
  f32x4 oacc[2][2] = {};
  const f32x4* bbase = (const f32x4*)(biaspf + ((size_t)(h * 36) * 512 + t) * 8);
  f32x4 bc[4];
#pragma unroll
  for (int i = 0; i < 4; ++i) bc[i] = bbase[(i >> 1) * 1024 + (i & 1)];
  const int xr0 = lo >> 3, xr1 = 2 | (lo >> 3);

  for (int kt2 = 0; kt2 < 18; ++kt2) {
    int ktn = (kt2 < 17) ? (kt2 + 1) : 17;
    f32x4 bn[4];
#pragma unroll
    for (int i = 0; i < 4; ++i) bn[i] = bbase[(2 * ktn + (i >> 1)) * 1024 + (i & 1)];

    i32x4 pw[2];
#pragma unroll
    for (int hf = 0; hf < 2; ++hf) {
      int kt = kt2 * 2 + hf;
      int krow = (kt * 16 + lo) * 36 + lg * 8;
      bf16x4 k0 = *(const bf16x4*)&Kl[krow];
      bf16x4 k1 = *(const bf16x4*)&Kl[krow + 4];
      bf16x8 kf = {k0[0], k0[1], k0[2], k0[3], k1[0], k1[1], k1[2], k1[3]};
#pragma unroll
      for (int qc = 0; qc < 2; ++qc) {
        f32x4 c = __builtin_amdgcn_mfma_f32_16x16x32_bf16(kf, qf[qc], bc[hf * 2 + qc], 0, 0, 0);
        float p0 = __builtin_amdgcn_exp2f(c[0]);
        float p1 = __builtin_amdgcn_exp2f(c[1]);
        float p2 = __builtin_amdgcn_exp2f(c[2]);
        float p3 = __builtin_amdgcn_exp2f(c[3]);
        ls[qc] += (p0 + p1) + (p2 + p3);
        pw[qc][hf * 2 + 0] = cvt_pk(p0, p1);
        pw[qc][hf * 2 + 1] = cvt_pk(p2, p3);
      }
    }
    int vb = kt2 * 32;
    bf16x8 vb0 = *(const bf16x8*)&VT[lo * 600 + vb + ((lg ^ xr0) & 3) * 8];
    bf16x8 vb1 = *(const bf16x8*)&VT[(16 + lo) * 600 + vb + ((lg ^ xr1) & 3) * 8];
#pragma unroll
    for (int qc = 0; qc < 2; ++qc) {
      bf16x8 pa = __builtin_bit_cast(bf16x8, pw[qc]);
      oacc[qc][0] = __builtin_amdgcn_mfma_f32_16x16x32_bf16(pa, vb0, oacc[qc][0], 0, 0, 0);
      oacc[qc][1] = __builtin_amdgcn_mfma_f32_16x16x32_bf16(pa, vb1, oacc[qc][1], 0, 0, 0);
    }
#pragma unroll
    for (int i = 0; i < 4; ++i) bc[i] = bn[i];
  }

#pragma unroll
  for (int qc = 0; qc < 2; ++qc) {
    float s = ls[qc];
    s += __shfl_xor(s, 16);
    s += __shfl_xor(s, 32);
    float linv = 1.0f / s;
#pragma unroll
    for (int r = 0; r < 4; ++r) {
      float lv = __shfl(linv, lg * 4 + r);
      int yy = wy * 16 + w * 2 + qc, xx = wx * 16 + lg * 4 + r;
      u16* dst = o_out + (size_t)((bb << 14) + yy * 128 + xx) * 192 + h * 32 + lo;
      dst[0]  = f2b(oacc[qc][0][r] * lv);
      dst[16] = f2b(oacc[qc][1][r] * lv);
    }
  }
}

// ---------------- launcher ---------------------------------------------------
extern "C" void kernel_launch(void* const* d_in, const int* in_sizes, int n_in,
                              void* d_out, int out_size, void* d_ws, size_t ws_size,
                              hipStream_t stream) {
  (void)in_sizes; (void)n_in; (void)out_size; (void)ws_size;
  const float* x      = (const float*)d_in[0];
  const float* n1g    = (const float*)d_in[1];
  const float* n1b    = (const float*)d_in[2];
  const float* qkv_w  = (const float*)d_in[3];
  const float* qkv_b  = (const float*)d_in[4];
  const float* rpb    = (const float*)d_in[5];
  const float* proj_w = (const float*)d_in[6];
  const float* proj_b = (const float*)d_in[7];
  const float* n2g    = (const float*)d_in[8];
  const float* n2b    = (const float*)d_in[9];
  const float* fc1_w  = (const float*)d_in[10];
  const float* fc1_b  = (const float*)d_in[11];
  const float* fc2_w  = (const float*)d_in[12];
  const float* fc2_b  = (const float*)d_in[13];

  char* ws = (char*)d_ws;
  u16*   wq     = (u16*)(ws + 0);          // 576x192 bf16
  u16*   wp     = (u16*)(ws + 221184);     // 192x192
  u16*   wf1    = (u16*)(ws + 294912);     // 384x192
  u16*   wf2    = (u16*)(ws + 442368);     // 192x384
  float* biaspf = (float*)(ws + 589824);   // packed rel-bias f32, 3538944 B
  u16*   obuf   = (u16*)(ws + 4194304);    // attn-out o bf16 (25 MB)
  u16*   qkvbuf = (u16*)(ws + 29360128);   // qkv bf16 (75.5 MB); later ybuf
  u16*   ybuf   = (u16*)(ws + 29360128);   // gelu(fc1) bf16 (50 MB, qkv dead then)
  u16*   xn2    = (u16*)(ws + 104857600);  // LN2 output bf16 (25 MB)
  u16*   x2     = (u16*)(ws + 130023424);  // post-proj residual bf16 (25 MB)

  wconv_kernel<<<dim3(6, 18), 256, 0, stream>>>(qkv_w, wq, 192, 576);
  wconv_kernel<<<dim3(6, 6),  256, 0, stream>>>(proj_w, wp, 192, 192);
  wconv_kernel<<<dim3(6, 12), 256, 0, stream>>>(fc1_w, wf1, 192, 384);
  wconv_kernel<<<dim3(12, 6), 256, 0, stream>>>(fc2_w, wf2, 384, 192);
  bias_pack_kernel<<<216, 512, 0, stream>>>(rpb, biaspf);

  gemm_as_kernel<576, 3, true><<<512, 256, 0, stream>>>(x, wq, qkv_b, n1g, n1b, qkvbuf);
  attn_kernel<<<1536, 512, 0, stream>>>(qkvbuf, biaspf, obuf);
  proj_ln_kernel<<<512, 256, 0, stream>>>(obuf, wp, proj_b, x, n2g, n2b, x2, xn2);
  gemm_as_kernel<384, 2, false><<<512, 256, 0, stream>>>(xn2, wf1, fc1_b, nullptr, nullptr, ybuf);
  gemm_kernel<192, 384, 5><<<1536, 256, 0, stream>>>(ybuf, wf2, fc2_b, x2, (float*)d_out);
}